// Round 13
// baseline (7545.145 us; speedup 1.0000x reference)
//
#include <hip/hip_runtime.h>
#include <math.h>

// DCRNN on MI355X — round 13: R12 + BN=128 for ALL diffusion variants
// (MFMA:LDS-read ratio 8:10 -> 16:12 per wave K-half-step; 48KB LDS -> 3 blocks/CU,
// grids 288/256/512 all single-pass). 2-term diffusion math unchanged —
// absmax must stay exactly 6.103516e-05.

#define NN 1024
#define BB 16
#define TT 12
#define HH 64
#define NB (NN*BB)      // 16384

typedef unsigned short u16;
typedef unsigned int u32;
typedef __attribute__((ext_vector_type(8))) short sv8;
typedef __attribute__((ext_vector_type(4))) float f32x4;
typedef __attribute__((ext_vector_type(16))) float f32x16;

__device__ __forceinline__ void gload16(const void* g, void* l) {
  __builtin_amdgcn_global_load_lds(
      (const __attribute__((address_space(1))) void*)(unsigned long long)(g),
      (__attribute__((address_space(3))) void*)(l), 16, 0, 0);
}

#define WAIT_BAR(N) asm volatile("s_waitcnt vmcnt(" #N ")\n\ts_barrier" ::: "memory")
#define BAR() asm volatile("s_barrier" ::: "memory")

template<int NX, int NY, int NZ>
__device__ __forceinline__ void xcdmap(int bid, int& x, int& y, int& z) {
  constexpr int ZREP = 8 / NZ;
  constexpr int YH = NY / ZREP;
  int chunk = bid & 7, pos = bid >> 3;
  z = chunk / ZREP;
  int yh = chunk % ZREP;
  x = pos % NX;
  y = yh * YH + pos / NX;
}

__device__ __forceinline__ int swz(int row, int g) {
  int rp = row >> 1;
  int j = ((row & 1) << 2) | g;
  return (rp << 3) | (j ^ (rp & 7));
}

__device__ __forceinline__ u16 bf16_rne(float x) {
  u32 u = __float_as_uint(x);
  return (u16)((u + 0x7FFFu + ((u >> 16) & 1u)) >> 16);
}
__device__ __forceinline__ void split2(float x, u16& h, u16& l) {
  h = bf16_rne(x);
  float hf = __uint_as_float(((u32)h) << 16);
  l = bf16_rne(x - hf);
}

__global__ __launch_bounds__(256) void k_zero(float* p, int n) {
  int i = blockIdx.x * 256 + threadIdx.x;
  if (i < n) p[i] = 0.f;
}

__global__ __launch_bounds__(256) void k_transpose_in(const float* __restrict__ in,
                                                      float* __restrict__ xt) {
  int idx = blockIdx.x * 256 + threadIdx.x;
  if (idx >= BB * TT * NN * 2) return;
  int i = idx & 1;
  int n = (idx >> 1) & (NN - 1);
  int bt = idx >> 11;
  int t = bt % TT, b = bt / TT;
  xt[(size_t)t * (NB * 2) + (size_t)(n * BB + b) * 2 + i] = in[idx];
}

__global__ __launch_bounds__(256) void k_splitS(const float* __restrict__ s,
                                                u16* __restrict__ sh, u16* __restrict__ sl) {
  int idx = blockIdx.x * 256 + threadIdx.x;
  if (idx >= 2 * NN * NN) return;
  u16 h, l; split2(s[idx], h, l);
  sh[idx] = h; sl[idx] = l;
}

__global__ __launch_bounds__(256) void k_transpS(const u16* __restrict__ sh,
        const u16* __restrict__ sl, u16* __restrict__ sth, u16* __restrict__ stl) {
  int idx = blockIdx.x * 256 + threadIdx.x;
  if (idx >= 2 * NN * NN) return;
  int j = idx & (NN - 1);
  int k = (idx >> 10) & (NN - 1);
  int z = idx >> 20;
  size_t src = ((size_t)z << 20) | ((size_t)j << 10) | (size_t)k;
  sth[idx] = sh[src];
  stl[idx] = sl[src];
}

__global__ __launch_bounds__(256) void k_padWt(const float* __restrict__ W,
        u16* __restrict__ Wth, u16* __restrict__ Wtl,
        int indim, int Dp, int KTa, int dout) {
  int idx = blockIdx.x * 256 + threadIdx.x;
  if (idx >= dout * KTa) return;
  int kk = idx % KTa, o = idx / KTa;
  int blk = kk / Dp, d = kk - blk * Dp;
  int Dreal = indim + 64;
  float v = 0.f;
  if (blk < 5) {
    int dorig = -1;
    if (d < 64) dorig = indim + d;
    else if (d - 64 < indim) dorig = d - 64;
    if (dorig >= 0) v = W[(size_t)(blk * Dreal + dorig) * dout + o];
  }
  u16 h, l; split2(v, h, l);
  Wth[idx] = h; Wtl[idx] = l;
}

__global__ __launch_bounds__(256) void k_padWtCand(const float* __restrict__ W,
        u16* __restrict__ Wth, u16* __restrict__ Wtl,
        int indim, int Dp, int KTa, int dout) {
  int idx = blockIdx.x * 256 + threadIdx.x;
  if (idx >= dout * KTa) return;
  int kk = idx % KTa, o = idx / KTa;
  int c = 64 + kk;
  int Dreal = indim + 64;
  float v = 0.f;
  if (c >= KTa) {
    int d = c - KTa;
    v = W[(size_t)(indim + d) * dout + o];
  } else {
    int blk = c / Dp, d = c - blk * Dp;
    if (blk == 0) {
      int di = d - 64;
      if (di < indim) v = W[(size_t)di * dout + o];
    } else {
      if (d < 64) v = W[(size_t)(blk * Dreal + indim + d) * dout + o];
      else if (d - 64 < indim) v = W[(size_t)(blk * Dreal + (d - 64)) * dout + o];
    }
  }
  u16 h, l; split2(v, h, l);
  Wth[idx] = h; Wtl[idx] = l;
}

struct PrepSeg {
  const float *inp, *st;
  u16 *ych, *ycl, *hh, *hl;
  int indim, CW, STR, nblk;
};
__global__ __launch_bounds__(256) void k_prepM(PrepSeg s0, PrepSeg s1) {
  const bool first = (int)blockIdx.x < s0.nblk;
  const PrepSeg s = first ? s0 : s1;
  const int c = first ? blockIdx.x : blockIdx.x - s0.nblk;
  int n0 = threadIdx.x << 2;
  int b = c / s.CW, d = c - b * s.CW;
  u16 h4[4], l4[4];
  #pragma unroll
  for (int r = 0; r < 4; r++) {
    int nb = ((n0 + r) << 4) + b;
    float v = 0.f;
    if (d < 64) v = s.st[(size_t)nb * HH + d];
    else if (d - 64 < s.indim) v = s.inp[(size_t)nb * s.indim + (d - 64)];
    split2(v, h4[r], l4[r]);
    s.hh[(size_t)nb * s.STR + d] = h4[r];
    s.hl[(size_t)nb * s.STR + d] = l4[r];
  }
  uint2 ph, pl;
  ph.x = (u32)h4[0] | ((u32)h4[1] << 16); ph.y = (u32)h4[2] | ((u32)h4[3] << 16);
  pl.x = (u32)l4[0] | ((u32)l4[1] << 16); pl.y = (u32)l4[2] | ((u32)l4[3] << 16);
  *(uint2*)&s.ych[(size_t)c * NN + n0] = ph;
  *(uint2*)&s.ycl[(size_t)c * NN + n0] = pl;
}

struct StageMap {
  int row1, g1, row2, g2;
  __device__ StageMap(int tid) {
    int rp = tid >> 3, jx = (tid & 7) ^ (rp & 7);
    row1 = (rp << 1) | (jx >> 2); g1 = jx & 3;
    int s = tid + 256; rp = s >> 3; jx = (s & 7) ^ (rp & 7);
    row2 = (rp << 1) | (jx >> 2); g2 = jx & 3;
  }
};

// ---------- S^2 (setup, runs once; full 3-term precision) ----------
__global__ __launch_bounds__(256) void k_sq(
    const u16* __restrict__ Sh, const u16* __restrict__ Sl,
    const u16* __restrict__ STh, const u16* __restrict__ STl,
    u16* __restrict__ Oh, u16* __restrict__ Ol)
{
  __shared__ __attribute__((aligned(16))) u16 lA[2][2][4096];
  __shared__ __attribute__((aligned(16))) u16 lB[2][2][4096];
  const int tid = threadIdx.x;
  const int lane = tid & 63, wave = tid >> 6;
  int bx, by, z;
  xcdmap<8, 8, 2>(blockIdx.x, bx, by, z);
  const int a0 = bx << 7, b0 = by << 7;
  const int wc0 = (wave & 1) << 6, wn0 = (wave >> 1) << 6;
  StageMap sm(tid);
  const u16* pa1h = Sh + (size_t)z * NN * NN + (size_t)(a0 + sm.row1) * NN + sm.g1 * 8;
  const u16* pa2h = Sh + (size_t)z * NN * NN + (size_t)(a0 + sm.row2) * NN + sm.g2 * 8;
  const u16* pa1l = Sl + (size_t)z * NN * NN + (size_t)(a0 + sm.row1) * NN + sm.g1 * 8;
  const u16* pa2l = Sl + (size_t)z * NN * NN + (size_t)(a0 + sm.row2) * NN + sm.g2 * 8;
  const u16* pb1h = STh + (size_t)z * NN * NN + (size_t)(b0 + sm.row1) * NN + sm.g1 * 8;
  const u16* pb2h = STh + (size_t)z * NN * NN + (size_t)(b0 + sm.row2) * NN + sm.g2 * 8;
  const u16* pb1l = STl + (size_t)z * NN * NN + (size_t)(b0 + sm.row1) * NN + sm.g1 * 8;
  const u16* pb2l = STl + (size_t)z * NN * NN + (size_t)(b0 + sm.row2) * NN + sm.g2 * 8;

  f32x16 acc[2][2];
  #pragma unroll
  for (int i = 0; i < 2; i++)
    #pragma unroll
    for (int j = 0; j < 2; j++)
      #pragma unroll
      for (int e = 0; e < 16; e++) acc[i][j][e] = 0.f;

  auto stage = [&](int buf, int k0) {
    gload16(pa1h + k0, &lA[buf][0][tid * 8]);
    gload16(pa2h + k0, &lA[buf][0][tid * 8 + 2048]);
    gload16(pa1l + k0, &lA[buf][1][tid * 8]);
    gload16(pa2l + k0, &lA[buf][1][tid * 8 + 2048]);
    gload16(pb1h + k0, &lB[buf][0][tid * 8]);
    gload16(pb2h + k0, &lB[buf][0][tid * 8 + 2048]);
    gload16(pb1l + k0, &lB[buf][1][tid * 8]);
    gload16(pb2l + k0, &lB[buf][1][tid * 8 + 2048]);
  };
  stage(0, 0);
  __syncthreads();
  int cur = 0;
  for (int kt = 0; kt < 32; kt++) {
    if (kt < 31) stage(cur ^ 1, (kt + 1) * 32);
    #pragma unroll
    for (int kh = 0; kh < 2; kh++) {
      sv8 vah[2], vaL[2], vbh[2], vbL[2];
      int gsel = (kh << 1) | (lane >> 5);
      #pragma unroll
      for (int f = 0; f < 2; f++) {
        int offa = swz(wc0 + f * 32 + (lane & 31), gsel) * 8;
        vah[f] = *(const sv8*)&lA[cur][0][offa];
        vaL[f] = *(const sv8*)&lA[cur][1][offa];
        int offb = swz(wn0 + f * 32 + (lane & 31), gsel) * 8;
        vbh[f] = *(const sv8*)&lB[cur][0][offb];
        vbL[f] = *(const sv8*)&lB[cur][1][offb];
      }
      #pragma unroll
      for (int fm = 0; fm < 2; fm++)
        #pragma unroll
        for (int fn = 0; fn < 2; fn++) {
          acc[fm][fn] = __builtin_amdgcn_mfma_f32_32x32x16_bf16(vah[fm], vbh[fn], acc[fm][fn], 0, 0, 0);
          acc[fm][fn] = __builtin_amdgcn_mfma_f32_32x32x16_bf16(vah[fm], vbL[fn], acc[fm][fn], 0, 0, 0);
          acc[fm][fn] = __builtin_amdgcn_mfma_f32_32x32x16_bf16(vaL[fm], vbh[fn], acc[fm][fn], 0, 0, 0);
        }
    }
    __syncthreads();
    cur ^= 1;
  }
  u16* oh = Oh + (size_t)z * NN * NN;
  u16* ol = Ol + (size_t)z * NN * NN;
  #pragma unroll
  for (int fm = 0; fm < 2; fm++)
    #pragma unroll
    for (int q = 0; q < 4; q++) {
      int m4 = a0 + wc0 + fm * 32 + q * 8 + ((lane >> 5) << 2);
      #pragma unroll
      for (int fn = 0; fn < 2; fn++) {
        int kc = b0 + wn0 + fn * 32 + (lane & 31);
        #pragma unroll
        for (int r = 0; r < 4; r++) {
          u16 hi, lo; split2(acc[fm][fn][q * 4 + r], hi, lo);
          oh[(size_t)(m4 + r) * NN + kc] = hi;
          ol[(size_t)(m4 + r) * NN + kc] = lo;
        }
      }
    }
}

// ---------- diffusion (BK=32, counted vmcnt, 2-term, BN=128 all variants) ----------
// V0 l0-full: CW72 DP72 KTA384 (9,8)->288   V1 l1-full: CW128 DP128 KTA640 (16,8)->512
// V2 l0-cand: CW64 DP72 KTA384 (8,8)->256   V3 l1-cand: CW64 DP128 KTA640 (8,8)->256
struct DiffSeg { const u16 *Ah, *Al; u16 *hh, *hl; int nblk; };

template<int V>
__device__ __forceinline__ void diffuse_body(int bid, const DiffSeg s,
    const u16* __restrict__ Sh, u16* sA, u16* sB)
{
  constexpr int DP  = (V == 0 || V == 2) ? 72 : 128;
  constexpr int KTA = (V == 0 || V == 2) ? 384 : 640;
  constexpr int STR = KTA + 64;
  constexpr int CW  = (V == 0) ? 72 : ((V == 1) ? 128 : 64);
  constexpr int NX  = (V == 0) ? 9 : ((V == 1) ? 16 : 8);

  const int tid = threadIdx.x;
  const int lane = tid & 63, wave = tid >> 6;
  int bx, by, z;
  xcdmap<NX, 8, 4>(bid, bx, by, z);
  const int a0 = bx << 7;
  const int b0 = by << 7;
  const int wc0 = (wave & 1) << 6;
  const int wn0 = (wave >> 1) << 6;
  StageMap sm(tid);
  const u16* pa1h = s.Ah + (size_t)(a0 + sm.row1) * NN + sm.g1 * 8;
  const u16* pa2h = s.Ah + (size_t)(a0 + sm.row2) * NN + sm.g2 * 8;
  const u16* pa1l = s.Al + (size_t)(a0 + sm.row1) * NN + sm.g1 * 8;
  const u16* pa2l = s.Al + (size_t)(a0 + sm.row2) * NN + sm.g2 * 8;
  const u16* pb1h = Sh + (size_t)z * NN * NN + (size_t)(b0 + sm.row1) * NN + sm.g1 * 8;
  const u16* pb2h = Sh + (size_t)z * NN * NN + (size_t)(b0 + sm.row2) * NN + sm.g2 * 8;

  f32x16 acc[2][2];
  #pragma unroll
  for (int i = 0; i < 2; i++)
    #pragma unroll
    for (int j = 0; j < 2; j++)
      #pragma unroll
      for (int e = 0; e < 16; e++) acc[i][j][e] = 0.f;

  auto stage = [&](int buf, int k0) {
    gload16(pa1h + k0, sA + (buf * 2 + 0) * 4096 + tid * 8);
    gload16(pa1l + k0, sA + (buf * 2 + 1) * 4096 + tid * 8);
    gload16(pa2h + k0, sA + (buf * 2 + 0) * 4096 + tid * 8 + 2048);
    gload16(pa2l + k0, sA + (buf * 2 + 1) * 4096 + tid * 8 + 2048);
    gload16(pb1h + k0, sB + buf * 4096 + tid * 8);
    gload16(pb2h + k0, sB + buf * 4096 + tid * 8 + 2048);
  };
  stage(0, 0);
  int cur = 0;
  for (int kt = 0; kt < 32; kt++) {
    if (kt < 31) {
      stage(cur ^ 1, (kt + 1) * 32);
      WAIT_BAR(6);
    } else {
      WAIT_BAR(0);
    }
    #pragma unroll
    for (int kh = 0; kh < 2; kh++) {
      sv8 vah[2], vaL[2], vbh[2];
      int gsel = (kh << 1) | (lane >> 5);
      #pragma unroll
      for (int f = 0; f < 2; f++) {
        int offa = swz(wc0 + f * 32 + (lane & 31), gsel) * 8;
        vah[f] = *(const sv8*)(sA + (cur * 2 + 0) * 4096 + offa);
        vaL[f] = *(const sv8*)(sA + (cur * 2 + 1) * 4096 + offa);
        int offb = swz(wn0 + f * 32 + (lane & 31), gsel) * 8;
        vbh[f] = *(const sv8*)(sB + cur * 4096 + offb);
      }
      #pragma unroll
      for (int fm = 0; fm < 2; fm++)
        #pragma unroll
        for (int fn = 0; fn < 2; fn++) {
          acc[fm][fn] = __builtin_amdgcn_mfma_f32_32x32x16_bf16(vah[fm], vbh[fn], acc[fm][fn], 0, 0, 0);
          acc[fm][fn] = __builtin_amdgcn_mfma_f32_32x32x16_bf16(vaL[fm], vbh[fn], acc[fm][fn], 0, 0, 0);
        }
    }
    BAR();
    cur ^= 1;
  }
  const int blkoff = (1 + ((z & 1) << 1) + (z >> 1)) * DP;
  #pragma unroll
  for (int fm = 0; fm < 2; fm++)
    #pragma unroll
    for (int q = 0; q < 4; q++) {
      int cg = a0 + wc0 + fm * 32 + q * 8 + ((lane >> 5) << 2);
      int bq = cg / CW, col = blkoff + (cg - bq * CW);
      #pragma unroll
      for (int fn = 0; fn < 2; fn++) {
        int mg = b0 + wn0 + fn * 32 + (lane & 31);
        u16 hi4[4], lo4[4];
        #pragma unroll
        for (int r = 0; r < 4; r++)
          split2(acc[fm][fn][q * 4 + r], hi4[r], lo4[r]);
        size_t hidx = (size_t)((mg << 4) + bq) * STR + col;
        uint2 ph, pl;
        ph.x = (u32)hi4[0] | ((u32)hi4[1] << 16); ph.y = (u32)hi4[2] | ((u32)hi4[3] << 16);
        pl.x = (u32)lo4[0] | ((u32)lo4[1] << 16); pl.y = (u32)lo4[2] | ((u32)lo4[3] << 16);
        *(uint2*)&s.hh[hidx] = ph;
        *(uint2*)&s.hl[hidx] = pl;
      }
    }
}

template<int VA, int VB>
__global__ __launch_bounds__(256) void k_diffM(DiffSeg s0, DiffSeg s1,
    const u16* __restrict__ Sh) {
  __shared__ __attribute__((aligned(16))) u16 sA[4 * 4096];
  __shared__ __attribute__((aligned(16))) u16 sB[2 * 4096];
  if ((int)blockIdx.x < s0.nblk) {
    diffuse_body<VA>(blockIdx.x, s0, Sh, sA, sB);
  } else {
    if constexpr (VB >= 0)
      diffuse_body<VB>(blockIdx.x - s0.nblk, s1, Sh, sA, sB);
  }
}

// ---------- gemm-ru (dbuf, counted vmcnt NL=3) + fused cand-prep ----------
struct G3RuSeg {
  const u16 *Ah, *Al, *Bh, *Bl;
  const float *bias, *stold;
  float *ru;
  u16 *ych, *ycl, *hh, *hl;
  int KTa, STR, nblk;
};
__global__ __launch_bounds__(512) void k_g3ru(G3RuSeg s0, G3RuSeg s1) {
  __shared__ __attribute__((aligned(16))) u16 lAh[2][2048];
  __shared__ __attribute__((aligned(16))) u16 lAl[2][2048];
  __shared__ __attribute__((aligned(16))) u16 lBh[2][4096];
  __shared__ __attribute__((aligned(16))) u16 lBl[2][4096];
  const bool first = (int)blockIdx.x < s0.nblk;
  const G3RuSeg s = first ? s0 : s1;
  const int bid = first ? blockIdx.x : blockIdx.x - s0.nblk;
  const int tid = threadIdx.x;
  const int lane = tid & 63, wave = tid >> 6;
  const int a0 = bid << 6;
  const int wr0 = (wave & 1) << 5;
  const int wn0 = (wave >> 1) << 5;
  const int gw = lane >> 4, rsel = lane & 15;
  const int sAi = tid & 255;
  int rp = sAi >> 3, jx = (sAi & 7) ^ (rp & 7);
  const int rowA = (rp << 1) | (jx >> 2), gAc = jx & 3;
  rp = tid >> 3; jx = (tid & 7) ^ (rp & 7);
  const int rowB = (rp << 1) | (jx >> 2), gBc = jx & 3;

  f32x4 acc[2][2];
  #pragma unroll
  for (int i = 0; i < 2; i++)
    #pragma unroll
    for (int j = 0; j < 2; j++) acc[i][j] = (f32x4){0.f, 0.f, 0.f, 0.f};

  auto stg = [&](int buf, int k0) {
    if (tid < 256) gload16(s.Ah + (size_t)(a0 + rowA) * s.STR + k0 + gAc * 8, &lAh[buf][sAi * 8]);
    else           gload16(s.Al + (size_t)(a0 + rowA) * s.STR + k0 + gAc * 8, &lAl[buf][sAi * 8]);
    gload16(s.Bh + (size_t)rowB * s.KTa + k0 + gBc * 8, &lBh[buf][tid * 8]);
    gload16(s.Bl + (size_t)rowB * s.KTa + k0 + gBc * 8, &lBl[buf][tid * 8]);
  };
  const int NI = s.KTa >> 5;
  stg(0, 0);
  int cur = 0;
  for (int i = 0; i < NI; i++) {
    if (i < NI - 1) {
      stg(cur ^ 1, (i + 1) * 32);
      WAIT_BAR(3);
    } else {
      WAIT_BAR(0);
    }
    sv8 vah[2], vaL[2], vbh[2], vbL[2];
    #pragma unroll
    for (int f = 0; f < 2; f++) {
      int offa = swz(wr0 + f * 16 + rsel, gw) * 8;
      vah[f] = *(const sv8*)&lAh[cur][offa];
      vaL[f] = *(const sv8*)&lAl[cur][offa];
      int offb = swz(wn0 + f * 16 + rsel, gw) * 8;
      vbh[f] = *(const sv8*)&lBh[cur][offb];
      vbL[f] = *(const sv8*)&lBl[cur][offb];
    }
    #pragma unroll
    for (int fm = 0; fm < 2; fm++)
      #pragma unroll
      for (int fn = 0; fn < 2; fn++) {
        acc[fm][fn] = __builtin_amdgcn_mfma_f32_16x16x32_bf16(vah[fm], vbh[fn], acc[fm][fn], 0, 0, 0);
        acc[fm][fn] = __builtin_amdgcn_mfma_f32_16x16x32_bf16(vah[fm], vbL[fn], acc[fm][fn], 0, 0, 0);
        acc[fm][fn] = __builtin_amdgcn_mfma_f32_16x16x32_bf16(vaL[fm], vbh[fn], acc[fm][fn], 0, 0, 0);
      }
    BAR();
    cur ^= 1;
  }

  #pragma unroll
  for (int fm = 0; fm < 2; fm++) {
    #pragma unroll
    for (int r = 0; r < 4; r++) {
      int nb = a0 + wr0 + fm * 16 + ((lane >> 4) << 2) + r;
      #pragma unroll
      for (int fn = 0; fn < 2; fn++) {
        int o = wn0 + fn * 16 + rsel;
        float v = acc[fm][fn][r] + s.bias[o];
        float sig = 1.f / (1.f + expf(-v));
        s.ru[(size_t)nb * 128 + o] = sig;
        if (o < 64) {
          float rv = sig * s.stold[(size_t)nb * HH + o];
          u16 hi, lo; split2(rv, hi, lo);
          int cc = ((nb & 15) << 6) + o;
          s.ych[(size_t)cc * NN + (nb >> 4)] = hi;
          s.ycl[(size_t)cc * NN + (nb >> 4)] = lo;
          s.hh[(size_t)nb * s.STR + s.KTa + o] = hi;
          s.hl[(size_t)nb * s.STR + s.KTa + o] = lo;
        }
      }
    }
  }
}

// ---------- gemm-cand (dbuf, NL=4) + fused next-cell prep + projection ----------
struct G3CdSeg {
  const u16 *Ah, *Al, *Bh, *Bl;
  const float *bias, *ru, *stold;
  float *stout;
  u16 *yAh, *yAl, *hAh, *hAl; int cwA, baseA, strA;
  u16 *yBh, *yBl, *hBh, *hBl; int cwB, baseB, strB;
  const float *ow, *ob;
  float *outg, *decin;
  u16 *yPh, *yPl, *hPh, *hPl; int cwP, baseP, strP;
  int t, KTa, STR, nblk;
};
__global__ __launch_bounds__(256) void k_g3cd(G3CdSeg s0, G3CdSeg s1) {
  __shared__ __attribute__((aligned(16))) u16 lAh[2][2048];
  __shared__ __attribute__((aligned(16))) u16 lAl[2][2048];
  __shared__ __attribute__((aligned(16))) u16 lBh[2][2048];
  __shared__ __attribute__((aligned(16))) u16 lBl[2][2048];
  __shared__ float pst[64][65];
  const bool first = (int)blockIdx.x < s0.nblk;
  const G3CdSeg s = first ? s0 : s1;
  const int bid = first ? blockIdx.x : blockIdx.x - s0.nblk;
  const int tid = threadIdx.x;
  const int lane = tid & 63, wave = tid >> 6;
  const int a0 = bid << 6;
  const int wr0 = (wave & 1) << 5;
  const int wn0 = (wave >> 1) << 5;
  const int gw = lane >> 4, rsel = lane & 15;
  int rp = tid >> 3, jx = (tid & 7) ^ (rp & 7);
  const int rowA = (rp << 1) | (jx >> 2), gAc = jx & 3;

  f32x4 acc[2][2];
  #pragma unroll
  for (int i = 0; i < 2; i++)
    #pragma unroll
    for (int j = 0; j < 2; j++) acc[i][j] = (f32x4){0.f, 0.f, 0.f, 0.f};

  auto stg = [&](int buf, int k0) {
    gload16(s.Ah + (size_t)(a0 + rowA) * s.STR + 64 + k0 + gAc * 8, &lAh[buf][tid * 8]);
    gload16(s.Al + (size_t)(a0 + rowA) * s.STR + 64 + k0 + gAc * 8, &lAl[buf][tid * 8]);
    gload16(s.Bh + (size_t)rowA * s.KTa + k0 + gAc * 8, &lBh[buf][tid * 8]);
    gload16(s.Bl + (size_t)rowA * s.KTa + k0 + gAc * 8, &lBl[buf][tid * 8]);
  };
  const int NI = s.KTa >> 5;
  stg(0, 0);
  int cur = 0;
  for (int i = 0; i < NI; i++) {
    if (i < NI - 1) {
      stg(cur ^ 1, (i + 1) * 32);
      WAIT_BAR(4);
    } else {
      WAIT_BAR(0);
    }
    sv8 vah[2], vaL[2], vbh[2], vbL[2];
    #pragma unroll
    for (int f = 0; f < 2; f++) {
      int offa = swz(wr0 + f * 16 + rsel, gw) * 8;
      vah[f] = *(const sv8*)&lAh[cur][offa];
      vaL[f] = *(const sv8*)&lAl[cur][offa];
      int offb = swz(wn0 + f * 16 + rsel, gw) * 8;
      vbh[f] = *(const sv8*)&lBh[cur][offb];
      vbL[f] = *(const sv8*)&lBl[cur][offb];
    }
    #pragma unroll
    for (int fm = 0; fm < 2; fm++)
      #pragma unroll
      for (int fn = 0; fn < 2; fn++) {
        acc[fm][fn] = __builtin_amdgcn_mfma_f32_16x16x32_bf16(vah[fm], vbh[fn], acc[fm][fn], 0, 0, 0);
        acc[fm][fn] = __builtin_amdgcn_mfma_f32_16x16x32_bf16(vah[fm], vbL[fn], acc[fm][fn], 0, 0, 0);
        acc[fm][fn] = __builtin_amdgcn_mfma_f32_16x16x32_bf16(vaL[fm], vbh[fn], acc[fm][fn], 0, 0, 0);
      }
    BAR();
    cur ^= 1;
  }

  #pragma unroll
  for (int fm = 0; fm < 2; fm++) {
    #pragma unroll
    for (int r = 0; r < 4; r++) {
      int nb = a0 + wr0 + fm * 16 + ((lane >> 4) << 2) + r;
      #pragma unroll
      for (int fn = 0; fn < 2; fn++) {
        int o = wn0 + fn * 16 + rsel;
        float v = acc[fm][fn][r] + s.bias[o];
        float u = s.ru[(size_t)nb * 128 + 64 + o];
        float sold = s.stold[(size_t)nb * HH + o];
        float ns = u * sold + (1.f - u) * tanhf(v);
        s.stout[(size_t)nb * HH + o] = ns;
        int b = nb & 15, n = nb >> 4;
        if (s.yAh) {
          u16 hi, lo; split2(ns, hi, lo);
          int c = b * s.cwA + s.baseA + o;
          s.yAh[(size_t)c * NN + n] = hi;
          s.yAl[(size_t)c * NN + n] = lo;
          s.hAh[(size_t)nb * s.strA + s.baseA + o] = hi;
          s.hAl[(size_t)nb * s.strA + s.baseA + o] = lo;
        }
        if (s.yBh) {
          u16 hi, lo; split2(ns, hi, lo);
          int c = b * s.cwB + s.baseB + o;
          s.yBh[(size_t)c * NN + n] = hi;
          s.yBl[(size_t)c * NN + n] = lo;
          s.hBh[(size_t)nb * s.strB + s.baseB + o] = hi;
          s.hBl[(size_t)nb * s.strB + s.baseB + o] = lo;
        }
        if (s.ow) pst[nb - a0][o] = ns;
      }
    }
  }
  if (s.ow) {
    __syncthreads();
    if (tid < 64) {
      int nb = a0 + tid;
      float a2 = s.ob[0];
      #pragma unroll
      for (int o = 0; o < HH; o++) a2 += pst[tid][o] * s.ow[o];
      int n = nb >> 4, b = nb & 15;
      s.outg[((size_t)b * TT + s.t) * NN + n] = a2;
      s.decin[nb] = a2;
      if (s.yPh) {
        u16 hi, lo; split2(a2, hi, lo);
        int c = b * s.cwP + s.baseP;
        s.yPh[(size_t)c * NN + n] = hi;
        s.yPl[(size_t)c * NN + n] = lo;
        s.hPh[(size_t)nb * s.strP + s.baseP] = hi;
        s.hPl[(size_t)nb * s.strP + s.baseP] = lo;
      }
    }
  }
}

// ---------------- host ----------------
struct LayerH {
  u16 *YcRh, *YcRl, *YcCh, *YcCl, *hh, *hl;
  float *ru;
  u16 *Wrh, *Wrl, *Wch, *Wcl;
  const float *br, *bc;
  int indim, CW, KTa, STR, nfull;
};

extern "C" void kernel_launch(void* const* d_in, const int* in_sizes, int n_in,
                              void* d_out, int out_size, void* d_ws, size_t ws_size,
                              hipStream_t stream) {
  const float* inputs   = (const float*)d_in[0];
  const float* supports = (const float*)d_in[1];
  const float* Wsrc[8] = {(const float*)d_in[2], (const float*)d_in[4],
                          (const float*)d_in[6], (const float*)d_in[8],
                          (const float*)d_in[10], (const float*)d_in[12],
                          (const float*)d_in[14], (const float*)d_in[16]};
  const float* bias[8] = {(const float*)d_in[3], (const float*)d_in[5],
                          (const float*)d_in[7], (const float*)d_in[9],
                          (const float*)d_in[11], (const float*)d_in[13],
                          (const float*)d_in[15], (const float*)d_in[17]};
  const float* outW = (const float*)d_in[18];
  const float* outB = (const float*)d_in[19];
  float* out = (float*)d_out;

  char* cur = (char*)d_ws;
  auto alloc = [&](size_t bytes) -> char* {
    char* p = cur; cur += (bytes + 255) & ~(size_t)255; return p;
  };
  u16* Sh    = (u16*)alloc((size_t)4 * NN * NN * 2);
  u16* Sl    = (u16*)alloc((size_t)4 * NN * NN * 2);
  u16* YcR0h = (u16*)alloc((size_t)1152 * NN * 2);
  u16* YcR0l = (u16*)alloc((size_t)1152 * NN * 2);
  u16* YcR1h = (u16*)alloc((size_t)2048 * NN * 2);
  u16* YcR1l = (u16*)alloc((size_t)2048 * NN * 2);
  u16* h0h   = (u16*)alloc((size_t)NB * 448 * 2);
  u16* h0l   = (u16*)alloc((size_t)NB * 448 * 2);
  u16* h1h   = (u16*)alloc((size_t)NB * 704 * 2);
  u16* h1l   = (u16*)alloc((size_t)NB * 704 * 2);
  float* ru0 = (float*)alloc((size_t)NB * 128 * 4);
  float* ru1 = (float*)alloc((size_t)NB * 128 * 4);
  float* P0  = (float*)alloc((size_t)NB * HH * 4);
  float* P1  = (float*)alloc((size_t)NB * HH * 4);
  float* st1 = (float*)alloc((size_t)NB * HH * 4);
  float* decin = (float*)alloc((size_t)NB * 4);
  float* xin = (float*)alloc((size_t)TT * NB * 2 * 4);
  u16* STh = h1h;
  u16* STl = h1l;
  u16* YcC0h = YcR0h; u16* YcC0l = YcR0l;
  u16* YcC1h = YcR1h; u16* YcC1l = YcR1l;

  const int wKTa[4]  = {384, 640, 384, 640};
  const int wIndim[4]= {2, 64, 1, 64};
  const int wDp[4]   = {72, 128, 72, 128};
  u16 *Wrh[4], *Wrl[4], *Wch[4], *Wcl[4];
  for (int i = 0; i < 4; i++) {
    Wrh[i] = (u16*)alloc((size_t)128 * wKTa[i] * 2);
    Wrl[i] = (u16*)alloc((size_t)128 * wKTa[i] * 2);
    Wch[i] = (u16*)alloc((size_t)64 * wKTa[i] * 2);
    Wcl[i] = (u16*)alloc((size_t)64 * wKTa[i] * 2);
  }

  auto blocks = [](int n) { return (n + 255) / 256; };
  k_zero<<<blocks(NB * HH), 256, 0, stream>>>(P1, NB * HH);
  k_zero<<<blocks(NB * HH), 256, 0, stream>>>(st1, NB * HH);
  k_zero<<<blocks(NB), 256, 0, stream>>>(decin, NB);
  k_transpose_in<<<blocks(BB * TT * NN * 2), 256, 0, stream>>>(inputs, xin);
  k_splitS<<<blocks(2 * NN * NN), 256, 0, stream>>>(supports, Sh, Sl);
  k_transpS<<<blocks(2 * NN * NN), 256, 0, stream>>>(Sh, Sl, STh, STl);
  k_sq<<<128, 256, 0, stream>>>(Sh, Sl, STh, STl,
                                Sh + (size_t)2 * NN * NN,
                                Sl + (size_t)2 * NN * NN);
  for (int i = 0; i < 4; i++) {
    k_padWt<<<blocks(128 * wKTa[i]), 256, 0, stream>>>(
        Wsrc[2 * i], Wrh[i], Wrl[i], wIndim[i], wDp[i], wKTa[i], 128);
    k_padWtCand<<<blocks(64 * wKTa[i]), 256, 0, stream>>>(
        Wsrc[2 * i + 1], Wch[i], Wcl[i], wIndim[i], wDp[i], wKTa[i], 64);
  }

  LayerH L[4];
  for (int i = 0; i < 4; i++) {
    bool lo = (wDp[i] == 72);
    L[i].YcRh = lo ? YcR0h : YcR1h; L[i].YcRl = lo ? YcR0l : YcR1l;
    L[i].YcCh = lo ? YcC0h : YcC1h; L[i].YcCl = lo ? YcC0l : YcC1l;
    L[i].hh = lo ? h0h : h1h; L[i].hl = lo ? h0l : h1l;
    L[i].ru = lo ? ru0 : ru1;
    L[i].Wrh = Wrh[i]; L[i].Wrl = Wrl[i]; L[i].Wch = Wch[i]; L[i].Wcl = Wcl[i];
    L[i].br = bias[2 * i]; L[i].bc = bias[2 * i + 1];
    L[i].indim = wIndim[i];
    L[i].CW = wDp[i]; L[i].KTa = wKTa[i]; L[i].STR = wKTa[i] + 64;
    L[i].nfull = lo ? 288 : 512;       // BN=128 grids
  }

  auto prepSeg = [&](LayerH& Y, const float* inp, const float* st) {
    return PrepSeg{inp, st, Y.YcRh, Y.YcRl, Y.hh, Y.hl, Y.indim, Y.CW, Y.STR, BB * Y.CW};
  };
  auto dRuSeg = [&](LayerH& Y) {
    return DiffSeg{Y.YcRh, Y.YcRl, Y.hh, Y.hl, Y.nfull};
  };
  auto dCdSeg = [&](LayerH& Y) {
    return DiffSeg{Y.YcCh, Y.YcCl, Y.hh, Y.hl, 256};
  };
  auto ruSeg = [&](LayerH& Y, const float* stold) {
    return G3RuSeg{Y.hh, Y.hl, Y.Wrh, Y.Wrl, Y.br, stold, Y.ru,
                   Y.YcCh, Y.YcCl, Y.hh, Y.hl, Y.KTa, Y.STR, NB / 64};
  };
  auto cdSeg = [&](LayerH& Y, const float* stold, float* stout,
                   const float* ow, const float* ob, int t) {
    G3CdSeg g{};
    g.Ah = Y.hh; g.Al = Y.hl; g.Bh = Y.Wch; g.Bl = Y.Wcl;
    g.bias = Y.bc; g.ru = Y.ru; g.stold = stold; g.stout = stout;
    g.ow = ow; g.ob = ob; g.outg = out; g.decin = decin;
    g.t = t; g.KTa = Y.KTa; g.STR = Y.STR; g.nblk = NB / 64;
    return g;
  };

  auto cell72 = [&](LayerH& Y, const float* inp, const float* stold, float* stout) {
    PrepSeg p = prepSeg(Y, inp, stold);
    k_prepM<<<p.nblk, 256, 0, stream>>>(p, p);
    DiffSeg dr = dRuSeg(Y);
    k_diffM<0, -1><<<dr.nblk, 256, 0, stream>>>(dr, dr, Sh);
    G3RuSeg gr = ruSeg(Y, stold);
    k_g3ru<<<gr.nblk, 512, 0, stream>>>(gr, gr);
    DiffSeg dc = dCdSeg(Y);
    k_diffM<2, -1><<<dc.nblk, 256, 0, stream>>>(dc, dc, Sh);
    G3CdSeg gc = cdSeg(Y, stold, stout, nullptr, nullptr, 0);
    k_g3cd<<<gc.nblk, 256, 0, stream>>>(gc, gc);
  };
  auto cell128 = [&](LayerH& Y, const float* inp, const float* stold, float* stout) {
    PrepSeg p = prepSeg(Y, inp, stold);
    k_prepM<<<p.nblk, 256, 0, stream>>>(p, p);
    DiffSeg dr = dRuSeg(Y);
    k_diffM<1, -1><<<dr.nblk, 256, 0, stream>>>(dr, dr, Sh);
    G3RuSeg gr = ruSeg(Y, stold);
    k_g3ru<<<gr.nblk, 512, 0, stream>>>(gr, gr);
    DiffSeg dc = dCdSeg(Y);
    k_diffM<3, -1><<<dc.nblk, 256, 0, stream>>>(dc, dc, Sh);
    G3CdSeg gc = cdSeg(Y, stold, stout, nullptr, nullptr, 0);
    k_g3cd<<<gc.nblk, 256, 0, stream>>>(gc, gc);
  };

  float* P[2] = {P0, P1};

  // ---- encoder: pipelined l0(t) ∥ l1(t-1) ----
  cell72(L[0], xin, P1, P0);
  for (int t = 1; t < TT; t++) {
    const float* Pold = P[(t - 1) & 1];
    float* Pnew = P[t & 1];
    PrepSeg p0 = prepSeg(L[0], xin + (size_t)t * NB * 2, Pold);
    PrepSeg p1 = prepSeg(L[1], Pold, st1);
    k_prepM<<<p0.nblk + p1.nblk, 256, 0, stream>>>(p0, p1);
    DiffSeg dr0 = dRuSeg(L[0]), dr1 = dRuSeg(L[1]);
    k_diffM<0, 1><<<dr0.nblk + dr1.nblk, 256, 0, stream>>>(dr0, dr1, Sh);
    G3RuSeg gr0 = ruSeg(L[0], Pold), gr1 = ruSeg(L[1], st1);
    k_g3ru<<<gr0.nblk + gr1.nblk, 512, 0, stream>>>(gr0, gr1);
    DiffSeg dc0 = dCdSeg(L[0]), dc1 = dCdSeg(L[1]);
    k_diffM<2, 3><<<dc0.nblk + dc1.nblk, 256, 0, stream>>>(dc0, dc1, Sh);
    G3CdSeg gc0 = cdSeg(L[0], Pold, Pnew, nullptr, nullptr, 0);
    G3CdSeg gc1 = cdSeg(L[1], st1, st1, nullptr, nullptr, 0);
    k_g3cd<<<gc0.nblk + gc1.nblk, 256, 0, stream>>>(gc0, gc1);
  }
  cell128(L[1], P[1], st1, st1);

  // ---- decoder: sequential, prep fused into g3cd epilogues ----
  {
    PrepSeg pd0 = prepSeg(L[2], decin, P1);
    PrepSeg pd1 = prepSeg(L[3], P1, st1);
    k_prepM<<<pd0.nblk + pd1.nblk, 256, 0, stream>>>(pd0, pd1);
  }
  for (int t = 0; t < TT; t++) {
    DiffSeg dr0 = dRuSeg(L[2]);
    k_diffM<0, -1><<<dr0.nblk, 256, 0, stream>>>(dr0, dr0, Sh);
    G3RuSeg gr0 = ruSeg(L[2], P1);
    k_g3ru<<<gr0.nblk, 512, 0, stream>>>(gr0, gr0);
    DiffSeg dc0 = dCdSeg(L[2]);
    k_diffM<2, -1><<<dc0.nblk, 256, 0, stream>>>(dc0, dc0, Sh);
    G3CdSeg g0 = cdSeg(L[2], P1, P1, nullptr, nullptr, 0);
    g0.yAh = L[2].YcRh; g0.yAl = L[2].YcRl; g0.hAh = L[2].hh; g0.hAl = L[2].hl;
    g0.cwA = 72; g0.baseA = 0; g0.strA = 448;
    g0.yBh = L[3].YcRh; g0.yBl = L[3].YcRl; g0.hBh = L[3].hh; g0.hBl = L[3].hl;
    g0.cwB = 128; g0.baseB = 64; g0.strB = 704;
    k_g3cd<<<g0.nblk, 256, 0, stream>>>(g0, g0);
    DiffSeg dr1 = dRuSeg(L[3]);
    k_diffM<1, -1><<<dr1.nblk, 256, 0, stream>>>(dr1, dr1, Sh);
    G3RuSeg gr1 = ruSeg(L[3], st1);
    k_g3ru<<<gr1.nblk, 512, 0, stream>>>(gr1, gr1);
    DiffSeg dc1 = dCdSeg(L[3]);
    k_diffM<3, -1><<<dc1.nblk, 256, 0, stream>>>(dc1, dc1, Sh);
    G3CdSeg g1 = cdSeg(L[3], st1, st1, outW, outB, t);
    g1.yAh = L[3].YcRh; g1.yAl = L[3].YcRl; g1.hAh = L[3].hh; g1.hAl = L[3].hl;
    g1.cwA = 128; g1.baseA = 0; g1.strA = 704;
    g1.yPh = L[2].YcRh; g1.yPl = L[2].YcRl; g1.hPh = L[2].hh; g1.hPl = L[2].hl;
    g1.cwP = 72; g1.baseP = 64; g1.strP = 448;
    k_g3cd<<<g1.nblk, 256, 0, stream>>>(g1, g1);
  }
}

// Round 14
// 6767.339 us; speedup vs baseline: 1.1149x; 1.1149x over previous
//
#include <hip/hip_runtime.h>
#include <math.h>

// DCRNN on MI355X — round 14: R12 structure (best: 7.20ms) + coalesced
// diffusion h-writes via LDS-transpose epilogue (2 passes hi/lo, [m][132]
// buffer). Old path wrote 8B per lane at ~22KB stride (8-13x HBM write
// amplification + RMW fetches). Values bit-identical: absmax must stay
// exactly 6.103516e-05.

#define NN 1024
#define BB 16
#define TT 12
#define HH 64
#define NB (NN*BB)      // 16384

typedef unsigned short u16;
typedef unsigned int u32;
typedef __attribute__((ext_vector_type(8))) short sv8;
typedef __attribute__((ext_vector_type(4))) float f32x4;
typedef __attribute__((ext_vector_type(16))) float f32x16;

__device__ __forceinline__ void gload16(const void* g, void* l) {
  __builtin_amdgcn_global_load_lds(
      (const __attribute__((address_space(1))) void*)(unsigned long long)(g),
      (__attribute__((address_space(3))) void*)(l), 16, 0, 0);
}

#define WAIT_BAR(N) asm volatile("s_waitcnt vmcnt(" #N ")\n\ts_barrier" ::: "memory")
#define BAR() asm volatile("s_barrier" ::: "memory")

template<int NX, int NY, int NZ>
__device__ __forceinline__ void xcdmap(int bid, int& x, int& y, int& z) {
  constexpr int ZREP = 8 / NZ;
  constexpr int YH = NY / ZREP;
  int chunk = bid & 7, pos = bid >> 3;
  z = chunk / ZREP;
  int yh = chunk % ZREP;
  x = pos % NX;
  y = yh * YH + pos / NX;
}

__device__ __forceinline__ int swz(int row, int g) {
  int rp = row >> 1;
  int j = ((row & 1) << 2) | g;
  return (rp << 3) | (j ^ (rp & 7));
}

__device__ __forceinline__ u16 bf16_rne(float x) {
  u32 u = __float_as_uint(x);
  return (u16)((u + 0x7FFFu + ((u >> 16) & 1u)) >> 16);
}
__device__ __forceinline__ void split2(float x, u16& h, u16& l) {
  h = bf16_rne(x);
  float hf = __uint_as_float(((u32)h) << 16);
  l = bf16_rne(x - hf);
}

__global__ __launch_bounds__(256) void k_zero(float* p, int n) {
  int i = blockIdx.x * 256 + threadIdx.x;
  if (i < n) p[i] = 0.f;
}

__global__ __launch_bounds__(256) void k_transpose_in(const float* __restrict__ in,
                                                      float* __restrict__ xt) {
  int idx = blockIdx.x * 256 + threadIdx.x;
  if (idx >= BB * TT * NN * 2) return;
  int i = idx & 1;
  int n = (idx >> 1) & (NN - 1);
  int bt = idx >> 11;
  int t = bt % TT, b = bt / TT;
  xt[(size_t)t * (NB * 2) + (size_t)(n * BB + b) * 2 + i] = in[idx];
}

__global__ __launch_bounds__(256) void k_splitS(const float* __restrict__ s,
                                                u16* __restrict__ sh, u16* __restrict__ sl) {
  int idx = blockIdx.x * 256 + threadIdx.x;
  if (idx >= 2 * NN * NN) return;
  u16 h, l; split2(s[idx], h, l);
  sh[idx] = h; sl[idx] = l;
}

__global__ __launch_bounds__(256) void k_transpS(const u16* __restrict__ sh,
        const u16* __restrict__ sl, u16* __restrict__ sth, u16* __restrict__ stl) {
  int idx = blockIdx.x * 256 + threadIdx.x;
  if (idx >= 2 * NN * NN) return;
  int j = idx & (NN - 1);
  int k = (idx >> 10) & (NN - 1);
  int z = idx >> 20;
  size_t src = ((size_t)z << 20) | ((size_t)j << 10) | (size_t)k;
  sth[idx] = sh[src];
  stl[idx] = sl[src];
}

__global__ __launch_bounds__(256) void k_padWt(const float* __restrict__ W,
        u16* __restrict__ Wth, u16* __restrict__ Wtl,
        int indim, int Dp, int KTa, int dout) {
  int idx = blockIdx.x * 256 + threadIdx.x;
  if (idx >= dout * KTa) return;
  int kk = idx % KTa, o = idx / KTa;
  int blk = kk / Dp, d = kk - blk * Dp;
  int Dreal = indim + 64;
  float v = 0.f;
  if (blk < 5) {
    int dorig = -1;
    if (d < 64) dorig = indim + d;
    else if (d - 64 < indim) dorig = d - 64;
    if (dorig >= 0) v = W[(size_t)(blk * Dreal + dorig) * dout + o];
  }
  u16 h, l; split2(v, h, l);
  Wth[idx] = h; Wtl[idx] = l;
}

__global__ __launch_bounds__(256) void k_padWtCand(const float* __restrict__ W,
        u16* __restrict__ Wth, u16* __restrict__ Wtl,
        int indim, int Dp, int KTa, int dout) {
  int idx = blockIdx.x * 256 + threadIdx.x;
  if (idx >= dout * KTa) return;
  int kk = idx % KTa, o = idx / KTa;
  int c = 64 + kk;
  int Dreal = indim + 64;
  float v = 0.f;
  if (c >= KTa) {
    int d = c - KTa;
    v = W[(size_t)(indim + d) * dout + o];
  } else {
    int blk = c / Dp, d = c - blk * Dp;
    if (blk == 0) {
      int di = d - 64;
      if (di < indim) v = W[(size_t)di * dout + o];
    } else {
      if (d < 64) v = W[(size_t)(blk * Dreal + indim + d) * dout + o];
      else if (d - 64 < indim) v = W[(size_t)(blk * Dreal + (d - 64)) * dout + o];
    }
  }
  u16 h, l; split2(v, h, l);
  Wth[idx] = h; Wtl[idx] = l;
}

struct PrepSeg {
  const float *inp, *st;
  u16 *ych, *ycl, *hh, *hl;
  int indim, CW, STR, nblk;
};
__global__ __launch_bounds__(256) void k_prepM(PrepSeg s0, PrepSeg s1) {
  const bool first = (int)blockIdx.x < s0.nblk;
  const PrepSeg s = first ? s0 : s1;
  const int c = first ? blockIdx.x : blockIdx.x - s0.nblk;
  int n0 = threadIdx.x << 2;
  int b = c / s.CW, d = c - b * s.CW;
  u16 h4[4], l4[4];
  #pragma unroll
  for (int r = 0; r < 4; r++) {
    int nb = ((n0 + r) << 4) + b;
    float v = 0.f;
    if (d < 64) v = s.st[(size_t)nb * HH + d];
    else if (d - 64 < s.indim) v = s.inp[(size_t)nb * s.indim + (d - 64)];
    split2(v, h4[r], l4[r]);
    s.hh[(size_t)nb * s.STR + d] = h4[r];
    s.hl[(size_t)nb * s.STR + d] = l4[r];
  }
  uint2 ph, pl;
  ph.x = (u32)h4[0] | ((u32)h4[1] << 16); ph.y = (u32)h4[2] | ((u32)h4[3] << 16);
  pl.x = (u32)l4[0] | ((u32)l4[1] << 16); pl.y = (u32)l4[2] | ((u32)l4[3] << 16);
  *(uint2*)&s.ych[(size_t)c * NN + n0] = ph;
  *(uint2*)&s.ycl[(size_t)c * NN + n0] = pl;
}

struct StageMap {
  int row1, g1, row2, g2;
  __device__ StageMap(int tid) {
    int rp = tid >> 3, jx = (tid & 7) ^ (rp & 7);
    row1 = (rp << 1) | (jx >> 2); g1 = jx & 3;
    int s = tid + 256; rp = s >> 3; jx = (s & 7) ^ (rp & 7);
    row2 = (rp << 1) | (jx >> 2); g2 = jx & 3;
  }
};

// ---------- S^2 (setup, runs once; full 3-term precision) ----------
__global__ __launch_bounds__(256) void k_sq(
    const u16* __restrict__ Sh, const u16* __restrict__ Sl,
    const u16* __restrict__ STh, const u16* __restrict__ STl,
    u16* __restrict__ Oh, u16* __restrict__ Ol)
{
  __shared__ __attribute__((aligned(16))) u16 lA[2][2][4096];
  __shared__ __attribute__((aligned(16))) u16 lB[2][2][4096];
  const int tid = threadIdx.x;
  const int lane = tid & 63, wave = tid >> 6;
  int bx, by, z;
  xcdmap<8, 8, 2>(blockIdx.x, bx, by, z);
  const int a0 = bx << 7, b0 = by << 7;
  const int wc0 = (wave & 1) << 6, wn0 = (wave >> 1) << 6;
  StageMap sm(tid);
  const u16* pa1h = Sh + (size_t)z * NN * NN + (size_t)(a0 + sm.row1) * NN + sm.g1 * 8;
  const u16* pa2h = Sh + (size_t)z * NN * NN + (size_t)(a0 + sm.row2) * NN + sm.g2 * 8;
  const u16* pa1l = Sl + (size_t)z * NN * NN + (size_t)(a0 + sm.row1) * NN + sm.g1 * 8;
  const u16* pa2l = Sl + (size_t)z * NN * NN + (size_t)(a0 + sm.row2) * NN + sm.g2 * 8;
  const u16* pb1h = STh + (size_t)z * NN * NN + (size_t)(b0 + sm.row1) * NN + sm.g1 * 8;
  const u16* pb2h = STh + (size_t)z * NN * NN + (size_t)(b0 + sm.row2) * NN + sm.g2 * 8;
  const u16* pb1l = STl + (size_t)z * NN * NN + (size_t)(b0 + sm.row1) * NN + sm.g1 * 8;
  const u16* pb2l = STl + (size_t)z * NN * NN + (size_t)(b0 + sm.row2) * NN + sm.g2 * 8;

  f32x16 acc[2][2];
  #pragma unroll
  for (int i = 0; i < 2; i++)
    #pragma unroll
    for (int j = 0; j < 2; j++)
      #pragma unroll
      for (int e = 0; e < 16; e++) acc[i][j][e] = 0.f;

  auto stage = [&](int buf, int k0) {
    gload16(pa1h + k0, &lA[buf][0][tid * 8]);
    gload16(pa2h + k0, &lA[buf][0][tid * 8 + 2048]);
    gload16(pa1l + k0, &lA[buf][1][tid * 8]);
    gload16(pa2l + k0, &lA[buf][1][tid * 8 + 2048]);
    gload16(pb1h + k0, &lB[buf][0][tid * 8]);
    gload16(pb2h + k0, &lB[buf][0][tid * 8 + 2048]);
    gload16(pb1l + k0, &lB[buf][1][tid * 8]);
    gload16(pb2l + k0, &lB[buf][1][tid * 8 + 2048]);
  };
  stage(0, 0);
  __syncthreads();
  int cur = 0;
  for (int kt = 0; kt < 32; kt++) {
    if (kt < 31) stage(cur ^ 1, (kt + 1) * 32);
    #pragma unroll
    for (int kh = 0; kh < 2; kh++) {
      sv8 vah[2], vaL[2], vbh[2], vbL[2];
      int gsel = (kh << 1) | (lane >> 5);
      #pragma unroll
      for (int f = 0; f < 2; f++) {
        int offa = swz(wc0 + f * 32 + (lane & 31), gsel) * 8;
        vah[f] = *(const sv8*)&lA[cur][0][offa];
        vaL[f] = *(const sv8*)&lA[cur][1][offa];
        int offb = swz(wn0 + f * 32 + (lane & 31), gsel) * 8;
        vbh[f] = *(const sv8*)&lB[cur][0][offb];
        vbL[f] = *(const sv8*)&lB[cur][1][offb];
      }
      #pragma unroll
      for (int fm = 0; fm < 2; fm++)
        #pragma unroll
        for (int fn = 0; fn < 2; fn++) {
          acc[fm][fn] = __builtin_amdgcn_mfma_f32_32x32x16_bf16(vah[fm], vbh[fn], acc[fm][fn], 0, 0, 0);
          acc[fm][fn] = __builtin_amdgcn_mfma_f32_32x32x16_bf16(vah[fm], vbL[fn], acc[fm][fn], 0, 0, 0);
          acc[fm][fn] = __builtin_amdgcn_mfma_f32_32x32x16_bf16(vaL[fm], vbh[fn], acc[fm][fn], 0, 0, 0);
        }
    }
    __syncthreads();
    cur ^= 1;
  }
  u16* oh = Oh + (size_t)z * NN * NN;
  u16* ol = Ol + (size_t)z * NN * NN;
  #pragma unroll
  for (int fm = 0; fm < 2; fm++)
    #pragma unroll
    for (int q = 0; q < 4; q++) {
      int m4 = a0 + wc0 + fm * 32 + q * 8 + ((lane >> 5) << 2);
      #pragma unroll
      for (int fn = 0; fn < 2; fn++) {
        int kc = b0 + wn0 + fn * 32 + (lane & 31);
        #pragma unroll
        for (int r = 0; r < 4; r++) {
          u16 hi, lo; split2(acc[fm][fn][q * 4 + r], hi, lo);
          oh[(size_t)(m4 + r) * NN + kc] = hi;
          ol[(size_t)(m4 + r) * NN + kc] = lo;
        }
      }
    }
}

// ---------- diffusion (BK=32, counted vmcnt, 2-term, coalesced epilogue) ----------
// V0 l0-full: BN64 (9,16)   V1 l1-full: BN128 (16,8)
// V2 l0-cand: BN64 (8,16)   V3 l1-cand: BN64 (8,16)
struct DiffSeg { const u16 *Ah, *Al; u16 *hh, *hl; int nblk; };

constexpr int bn_of(int V) { return (V == 1) ? 128 : 64; }

template<int V>
__device__ __forceinline__ void diffuse_body(int bid, const DiffSeg s,
    const u16* __restrict__ Sh, u16* lds)
{
  constexpr int BN  = bn_of(V);
  constexpr int DP  = (V == 0 || V == 2) ? 72 : 128;
  constexpr int KTA = (V == 0 || V == 2) ? 384 : 640;
  constexpr int STR = KTA + 64;
  constexpr int CW  = (V == 0) ? 72 : ((V == 1) ? 128 : 64);
  constexpr int NX  = (V == 0) ? 9 : ((V == 1) ? 16 : 8);
  constexpr int NY  = (BN == 128) ? 8 : 16;
  constexpr int FN  = BN / 64;

  u16* sA = lds;
  u16* sB = lds + 4 * 4096;
  const int tid = threadIdx.x;
  const int lane = tid & 63, wave = tid >> 6;
  int bx, by, z;
  xcdmap<NX, NY, 4>(bid, bx, by, z);
  const int a0 = bx << 7;
  const int b0 = by * BN;
  const int wc0 = (wave & 1) << 6;
  const int wn0 = (wave >> 1) * (BN / 2);
  StageMap sm(tid);
  const u16* pa1h = s.Ah + (size_t)(a0 + sm.row1) * NN + sm.g1 * 8;
  const u16* pa2h = s.Ah + (size_t)(a0 + sm.row2) * NN + sm.g2 * 8;
  const u16* pa1l = s.Al + (size_t)(a0 + sm.row1) * NN + sm.g1 * 8;
  const u16* pa2l = s.Al + (size_t)(a0 + sm.row2) * NN + sm.g2 * 8;
  const u16* pb1h = Sh + (size_t)z * NN * NN + (size_t)(b0 + sm.row1) * NN + sm.g1 * 8;
  const u16* pb2h = Sh + (size_t)z * NN * NN + (size_t)(b0 + sm.row2) * NN + sm.g2 * 8;

  f32x16 acc[2][FN];
  #pragma unroll
  for (int i = 0; i < 2; i++)
    #pragma unroll
    for (int j = 0; j < FN; j++)
      #pragma unroll
      for (int e = 0; e < 16; e++) acc[i][j][e] = 0.f;

  auto stage = [&](int buf, int k0) {
    gload16(pa1h + k0, sA + (buf * 2 + 0) * 4096 + tid * 8);
    gload16(pa1l + k0, sA + (buf * 2 + 1) * 4096 + tid * 8);
    gload16(pa2h + k0, sA + (buf * 2 + 0) * 4096 + tid * 8 + 2048);
    gload16(pa2l + k0, sA + (buf * 2 + 1) * 4096 + tid * 8 + 2048);
    gload16(pb1h + k0, sB + buf * (BN * 32) + tid * 8);
    if constexpr (BN == 128)
      gload16(pb2h + k0, sB + buf * (BN * 32) + tid * 8 + 2048);
  };
  stage(0, 0);
  int cur = 0;
  for (int kt = 0; kt < 32; kt++) {
    if (kt < 31) {
      stage(cur ^ 1, (kt + 1) * 32);
      if constexpr (BN == 128) { WAIT_BAR(6); } else { WAIT_BAR(5); }
    } else {
      WAIT_BAR(0);
    }
    #pragma unroll
    for (int kh = 0; kh < 2; kh++) {
      sv8 vah[2], vaL[2], vbh[FN];
      int gsel = (kh << 1) | (lane >> 5);
      #pragma unroll
      for (int f = 0; f < 2; f++) {
        int offa = swz(wc0 + f * 32 + (lane & 31), gsel) * 8;
        vah[f] = *(const sv8*)(sA + (cur * 2 + 0) * 4096 + offa);
        vaL[f] = *(const sv8*)(sA + (cur * 2 + 1) * 4096 + offa);
      }
      #pragma unroll
      for (int f = 0; f < FN; f++) {
        int offb = swz(wn0 + f * 32 + (lane & 31), gsel) * 8;
        vbh[f] = *(const sv8*)(sB + cur * (BN * 32) + offb);
      }
      #pragma unroll
      for (int fm = 0; fm < 2; fm++)
        #pragma unroll
        for (int fn = 0; fn < FN; fn++) {
          acc[fm][fn] = __builtin_amdgcn_mfma_f32_32x32x16_bf16(vah[fm], vbh[fn], acc[fm][fn], 0, 0, 0);
          acc[fm][fn] = __builtin_amdgcn_mfma_f32_32x32x16_bf16(vaL[fm], vbh[fn], acc[fm][fn], 0, 0, 0);
        }
    }
    BAR();
    cur ^= 1;
  }

  // ---- coalesced epilogue: LDS transpose [m][132], two passes (hi, lo) ----
  const int blkoff = (1 + ((z & 1) << 1) + (z >> 1)) * DP;
  u16* const dsts[2] = {s.hh, s.hl};
  #pragma unroll
  for (int p = 0; p < 2; p++) {
    #pragma unroll
    for (int fm = 0; fm < 2; fm++)
      #pragma unroll
      for (int q = 0; q < 4; q++) {
        int cl = wc0 + fm * 32 + q * 8 + ((lane >> 5) << 2);
        #pragma unroll
        for (int fn = 0; fn < FN; fn++) {
          int ml = wn0 + fn * 32 + (lane & 31);
          u16 v4[4];
          #pragma unroll
          for (int r = 0; r < 4; r++) {
            u16 hi, lo; split2(acc[fm][fn][q * 4 + r], hi, lo);
            v4[r] = p ? lo : hi;
          }
          uint2 pk;
          pk.x = (u32)v4[0] | ((u32)v4[1] << 16);
          pk.y = (u32)v4[2] | ((u32)v4[3] << 16);
          *(uint2*)&lds[ml * 132 + cl] = pk;
        }
      }
    __syncthreads();
    u16* dst = dsts[p];
    #pragma unroll
    for (int i = 0; i < BN * 32 / 256; i++) {
      int w = tid + (i << 8);
      int ml = w >> 5, c4 = (w & 31) << 2;
      uint2 pk = *(uint2*)&lds[ml * 132 + c4];
      int cg = a0 + c4;
      int bq = cg / CW, dq = cg - bq * CW;
      int nb = ((b0 + ml) << 4) + bq;
      *(uint2*)&dst[(size_t)nb * STR + blkoff + dq] = pk;
    }
    __syncthreads();
  }
}

template<int VA, int VB>
__global__ __launch_bounds__(256) void k_diffM(DiffSeg s0, DiffSeg s1,
    const u16* __restrict__ Sh) {
  constexpr int BNA = bn_of(VA);
  constexpr int BNB = (VB >= 0) ? bn_of(VB) : 64;
  constexpr int MB = BNA > BNB ? BNA : BNB;
  constexpr int STG = 4 * 4096 + 2 * MB * 32;
  constexpr int TRN = MB * 132;
  constexpr int TOT = STG > TRN ? STG : TRN;
  __shared__ __attribute__((aligned(16))) u16 lds[TOT];
  if ((int)blockIdx.x < s0.nblk) {
    diffuse_body<VA>(blockIdx.x, s0, Sh, lds);
  } else {
    if constexpr (VB >= 0)
      diffuse_body<VB>(blockIdx.x - s0.nblk, s1, Sh, lds);
  }
}

// ---------- gemm-ru (dbuf, counted vmcnt NL=3) + fused cand-prep ----------
struct G3RuSeg {
  const u16 *Ah, *Al, *Bh, *Bl;
  const float *bias, *stold;
  float *ru;
  u16 *ych, *ycl, *hh, *hl;
  int KTa, STR, nblk;
};
__global__ __launch_bounds__(512) void k_g3ru(G3RuSeg s0, G3RuSeg s1) {
  __shared__ __attribute__((aligned(16))) u16 lAh[2][2048];
  __shared__ __attribute__((aligned(16))) u16 lAl[2][2048];
  __shared__ __attribute__((aligned(16))) u16 lBh[2][4096];
  __shared__ __attribute__((aligned(16))) u16 lBl[2][4096];
  const bool first = (int)blockIdx.x < s0.nblk;
  const G3RuSeg s = first ? s0 : s1;
  const int bid = first ? blockIdx.x : blockIdx.x - s0.nblk;
  const int tid = threadIdx.x;
  const int lane = tid & 63, wave = tid >> 6;
  const int a0 = bid << 6;
  const int wr0 = (wave & 1) << 5;
  const int wn0 = (wave >> 1) << 5;
  const int gw = lane >> 4, rsel = lane & 15;
  const int sAi = tid & 255;
  int rp = sAi >> 3, jx = (sAi & 7) ^ (rp & 7);
  const int rowA = (rp << 1) | (jx >> 2), gAc = jx & 3;
  rp = tid >> 3; jx = (tid & 7) ^ (rp & 7);
  const int rowB = (rp << 1) | (jx >> 2), gBc = jx & 3;

  f32x4 acc[2][2];
  #pragma unroll
  for (int i = 0; i < 2; i++)
    #pragma unroll
    for (int j = 0; j < 2; j++) acc[i][j] = (f32x4){0.f, 0.f, 0.f, 0.f};

  auto stg = [&](int buf, int k0) {
    if (tid < 256) gload16(s.Ah + (size_t)(a0 + rowA) * s.STR + k0 + gAc * 8, &lAh[buf][sAi * 8]);
    else           gload16(s.Al + (size_t)(a0 + rowA) * s.STR + k0 + gAc * 8, &lAl[buf][sAi * 8]);
    gload16(s.Bh + (size_t)rowB * s.KTa + k0 + gBc * 8, &lBh[buf][tid * 8]);
    gload16(s.Bl + (size_t)rowB * s.KTa + k0 + gBc * 8, &lBl[buf][tid * 8]);
  };
  const int NI = s.KTa >> 5;
  stg(0, 0);
  int cur = 0;
  for (int i = 0; i < NI; i++) {
    if (i < NI - 1) {
      stg(cur ^ 1, (i + 1) * 32);
      WAIT_BAR(3);
    } else {
      WAIT_BAR(0);
    }
    sv8 vah[2], vaL[2], vbh[2], vbL[2];
    #pragma unroll
    for (int f = 0; f < 2; f++) {
      int offa = swz(wr0 + f * 16 + rsel, gw) * 8;
      vah[f] = *(const sv8*)&lAh[cur][offa];
      vaL[f] = *(const sv8*)&lAl[cur][offa];
      int offb = swz(wn0 + f * 16 + rsel, gw) * 8;
      vbh[f] = *(const sv8*)&lBh[cur][offb];
      vbL[f] = *(const sv8*)&lBl[cur][offb];
    }
    #pragma unroll
    for (int fm = 0; fm < 2; fm++)
      #pragma unroll
      for (int fn = 0; fn < 2; fn++) {
        acc[fm][fn] = __builtin_amdgcn_mfma_f32_16x16x32_bf16(vah[fm], vbh[fn], acc[fm][fn], 0, 0, 0);
        acc[fm][fn] = __builtin_amdgcn_mfma_f32_16x16x32_bf16(vah[fm], vbL[fn], acc[fm][fn], 0, 0, 0);
        acc[fm][fn] = __builtin_amdgcn_mfma_f32_16x16x32_bf16(vaL[fm], vbh[fn], acc[fm][fn], 0, 0, 0);
      }
    BAR();
    cur ^= 1;
  }

  #pragma unroll
  for (int fm = 0; fm < 2; fm++) {
    #pragma unroll
    for (int r = 0; r < 4; r++) {
      int nb = a0 + wr0 + fm * 16 + ((lane >> 4) << 2) + r;
      #pragma unroll
      for (int fn = 0; fn < 2; fn++) {
        int o = wn0 + fn * 16 + rsel;
        float v = acc[fm][fn][r] + s.bias[o];
        float sig = 1.f / (1.f + expf(-v));
        s.ru[(size_t)nb * 128 + o] = sig;
        if (o < 64) {
          float rv = sig * s.stold[(size_t)nb * HH + o];
          u16 hi, lo; split2(rv, hi, lo);
          int cc = ((nb & 15) << 6) + o;
          s.ych[(size_t)cc * NN + (nb >> 4)] = hi;
          s.ycl[(size_t)cc * NN + (nb >> 4)] = lo;
          s.hh[(size_t)nb * s.STR + s.KTa + o] = hi;
          s.hl[(size_t)nb * s.STR + s.KTa + o] = lo;
        }
      }
    }
  }
}

// ---------- gemm-cand (dbuf, NL=4) + fused next-cell prep + projection ----------
struct G3CdSeg {
  const u16 *Ah, *Al, *Bh, *Bl;
  const float *bias, *ru, *stold;
  float *stout;
  u16 *yAh, *yAl, *hAh, *hAl; int cwA, baseA, strA;
  u16 *yBh, *yBl, *hBh, *hBl; int cwB, baseB, strB;
  const float *ow, *ob;
  float *outg, *decin;
  u16 *yPh, *yPl, *hPh, *hPl; int cwP, baseP, strP;
  int t, KTa, STR, nblk;
};
__global__ __launch_bounds__(256) void k_g3cd(G3CdSeg s0, G3CdSeg s1) {
  __shared__ __attribute__((aligned(16))) u16 lAh[2][2048];
  __shared__ __attribute__((aligned(16))) u16 lAl[2][2048];
  __shared__ __attribute__((aligned(16))) u16 lBh[2][2048];
  __shared__ __attribute__((aligned(16))) u16 lBl[2][2048];
  __shared__ float pst[64][65];
  const bool first = (int)blockIdx.x < s0.nblk;
  const G3CdSeg s = first ? s0 : s1;
  const int bid = first ? blockIdx.x : blockIdx.x - s0.nblk;
  const int tid = threadIdx.x;
  const int lane = tid & 63, wave = tid >> 6;
  const int a0 = bid << 6;
  const int wr0 = (wave & 1) << 5;
  const int wn0 = (wave >> 1) << 5;
  const int gw = lane >> 4, rsel = lane & 15;
  int rp = tid >> 3, jx = (tid & 7) ^ (rp & 7);
  const int rowA = (rp << 1) | (jx >> 2), gAc = jx & 3;

  f32x4 acc[2][2];
  #pragma unroll
  for (int i = 0; i < 2; i++)
    #pragma unroll
    for (int j = 0; j < 2; j++) acc[i][j] = (f32x4){0.f, 0.f, 0.f, 0.f};

  auto stg = [&](int buf, int k0) {
    gload16(s.Ah + (size_t)(a0 + rowA) * s.STR + 64 + k0 + gAc * 8, &lAh[buf][tid * 8]);
    gload16(s.Al + (size_t)(a0 + rowA) * s.STR + 64 + k0 + gAc * 8, &lAl[buf][tid * 8]);
    gload16(s.Bh + (size_t)rowA * s.KTa + k0 + gAc * 8, &lBh[buf][tid * 8]);
    gload16(s.Bl + (size_t)rowA * s.KTa + k0 + gAc * 8, &lBl[buf][tid * 8]);
  };
  const int NI = s.KTa >> 5;
  stg(0, 0);
  int cur = 0;
  for (int i = 0; i < NI; i++) {
    if (i < NI - 1) {
      stg(cur ^ 1, (i + 1) * 32);
      WAIT_BAR(4);
    } else {
      WAIT_BAR(0);
    }
    sv8 vah[2], vaL[2], vbh[2], vbL[2];
    #pragma unroll
    for (int f = 0; f < 2; f++) {
      int offa = swz(wr0 + f * 16 + rsel, gw) * 8;
      vah[f] = *(const sv8*)&lAh[cur][offa];
      vaL[f] = *(const sv8*)&lAl[cur][offa];
      int offb = swz(wn0 + f * 16 + rsel, gw) * 8;
      vbh[f] = *(const sv8*)&lBh[cur][offb];
      vbL[f] = *(const sv8*)&lBl[cur][offb];
    }
    #pragma unroll
    for (int fm = 0; fm < 2; fm++)
      #pragma unroll
      for (int fn = 0; fn < 2; fn++) {
        acc[fm][fn] = __builtin_amdgcn_mfma_f32_16x16x32_bf16(vah[fm], vbh[fn], acc[fm][fn], 0, 0, 0);
        acc[fm][fn] = __builtin_amdgcn_mfma_f32_16x16x32_bf16(vah[fm], vbL[fn], acc[fm][fn], 0, 0, 0);
        acc[fm][fn] = __builtin_amdgcn_mfma_f32_16x16x32_bf16(vaL[fm], vbh[fn], acc[fm][fn], 0, 0, 0);
      }
    BAR();
    cur ^= 1;
  }

  #pragma unroll
  for (int fm = 0; fm < 2; fm++) {
    #pragma unroll
    for (int r = 0; r < 4; r++) {
      int nb = a0 + wr0 + fm * 16 + ((lane >> 4) << 2) + r;
      #pragma unroll
      for (int fn = 0; fn < 2; fn++) {
        int o = wn0 + fn * 16 + rsel;
        float v = acc[fm][fn][r] + s.bias[o];
        float u = s.ru[(size_t)nb * 128 + 64 + o];
        float sold = s.stold[(size_t)nb * HH + o];
        float ns = u * sold + (1.f - u) * tanhf(v);
        s.stout[(size_t)nb * HH + o] = ns;
        int b = nb & 15, n = nb >> 4;
        if (s.yAh) {
          u16 hi, lo; split2(ns, hi, lo);
          int c = b * s.cwA + s.baseA + o;
          s.yAh[(size_t)c * NN + n] = hi;
          s.yAl[(size_t)c * NN + n] = lo;
          s.hAh[(size_t)nb * s.strA + s.baseA + o] = hi;
          s.hAl[(size_t)nb * s.strA + s.baseA + o] = lo;
        }
        if (s.yBh) {
          u16 hi, lo; split2(ns, hi, lo);
          int c = b * s.cwB + s.baseB + o;
          s.yBh[(size_t)c * NN + n] = hi;
          s.yBl[(size_t)c * NN + n] = lo;
          s.hBh[(size_t)nb * s.strB + s.baseB + o] = hi;
          s.hBl[(size_t)nb * s.strB + s.baseB + o] = lo;
        }
        if (s.ow) pst[nb - a0][o] = ns;
      }
    }
  }
  if (s.ow) {
    __syncthreads();
    if (tid < 64) {
      int nb = a0 + tid;
      float a2 = s.ob[0];
      #pragma unroll
      for (int o = 0; o < HH; o++) a2 += pst[tid][o] * s.ow[o];
      int n = nb >> 4, b = nb & 15;
      s.outg[((size_t)b * TT + s.t) * NN + n] = a2;
      s.decin[nb] = a2;
      if (s.yPh) {
        u16 hi, lo; split2(a2, hi, lo);
        int c = b * s.cwP + s.baseP;
        s.yPh[(size_t)c * NN + n] = hi;
        s.yPl[(size_t)c * NN + n] = lo;
        s.hPh[(size_t)nb * s.strP + s.baseP] = hi;
        s.hPl[(size_t)nb * s.strP + s.baseP] = lo;
      }
    }
  }
}

// ---------------- host ----------------
struct LayerH {
  u16 *YcRh, *YcRl, *YcCh, *YcCl, *hh, *hl;
  float *ru;
  u16 *Wrh, *Wrl, *Wch, *Wcl;
  const float *br, *bc;
  int indim, CW, KTa, STR, nfull;
};

extern "C" void kernel_launch(void* const* d_in, const int* in_sizes, int n_in,
                              void* d_out, int out_size, void* d_ws, size_t ws_size,
                              hipStream_t stream) {
  const float* inputs   = (const float*)d_in[0];
  const float* supports = (const float*)d_in[1];
  const float* Wsrc[8] = {(const float*)d_in[2], (const float*)d_in[4],
                          (const float*)d_in[6], (const float*)d_in[8],
                          (const float*)d_in[10], (const float*)d_in[12],
                          (const float*)d_in[14], (const float*)d_in[16]};
  const float* bias[8] = {(const float*)d_in[3], (const float*)d_in[5],
                          (const float*)d_in[7], (const float*)d_in[9],
                          (const float*)d_in[11], (const float*)d_in[13],
                          (const float*)d_in[15], (const float*)d_in[17]};
  const float* outW = (const float*)d_in[18];
  const float* outB = (const float*)d_in[19];
  float* out = (float*)d_out;

  char* cur = (char*)d_ws;
  auto alloc = [&](size_t bytes) -> char* {
    char* p = cur; cur += (bytes + 255) & ~(size_t)255; return p;
  };
  u16* Sh    = (u16*)alloc((size_t)4 * NN * NN * 2);
  u16* Sl    = (u16*)alloc((size_t)4 * NN * NN * 2);
  u16* YcR0h = (u16*)alloc((size_t)1152 * NN * 2);
  u16* YcR0l = (u16*)alloc((size_t)1152 * NN * 2);
  u16* YcR1h = (u16*)alloc((size_t)2048 * NN * 2);
  u16* YcR1l = (u16*)alloc((size_t)2048 * NN * 2);
  u16* h0h   = (u16*)alloc((size_t)NB * 448 * 2);
  u16* h0l   = (u16*)alloc((size_t)NB * 448 * 2);
  u16* h1h   = (u16*)alloc((size_t)NB * 704 * 2);
  u16* h1l   = (u16*)alloc((size_t)NB * 704 * 2);
  float* ru0 = (float*)alloc((size_t)NB * 128 * 4);
  float* ru1 = (float*)alloc((size_t)NB * 128 * 4);
  float* P0  = (float*)alloc((size_t)NB * HH * 4);
  float* P1  = (float*)alloc((size_t)NB * HH * 4);
  float* st1 = (float*)alloc((size_t)NB * HH * 4);
  float* decin = (float*)alloc((size_t)NB * 4);
  float* xin = (float*)alloc((size_t)TT * NB * 2 * 4);
  u16* STh = h1h;
  u16* STl = h1l;
  u16* YcC0h = YcR0h; u16* YcC0l = YcR0l;
  u16* YcC1h = YcR1h; u16* YcC1l = YcR1l;

  const int wKTa[4]  = {384, 640, 384, 640};
  const int wIndim[4]= {2, 64, 1, 64};
  const int wDp[4]   = {72, 128, 72, 128};
  u16 *Wrh[4], *Wrl[4], *Wch[4], *Wcl[4];
  for (int i = 0; i < 4; i++) {
    Wrh[i] = (u16*)alloc((size_t)128 * wKTa[i] * 2);
    Wrl[i] = (u16*)alloc((size_t)128 * wKTa[i] * 2);
    Wch[i] = (u16*)alloc((size_t)64 * wKTa[i] * 2);
    Wcl[i] = (u16*)alloc((size_t)64 * wKTa[i] * 2);
  }

  auto blocks = [](int n) { return (n + 255) / 256; };
  k_zero<<<blocks(NB * HH), 256, 0, stream>>>(P1, NB * HH);
  k_zero<<<blocks(NB * HH), 256, 0, stream>>>(st1, NB * HH);
  k_zero<<<blocks(NB), 256, 0, stream>>>(decin, NB);
  k_transpose_in<<<blocks(BB * TT * NN * 2), 256, 0, stream>>>(inputs, xin);
  k_splitS<<<blocks(2 * NN * NN), 256, 0, stream>>>(supports, Sh, Sl);
  k_transpS<<<blocks(2 * NN * NN), 256, 0, stream>>>(Sh, Sl, STh, STl);
  k_sq<<<128, 256, 0, stream>>>(Sh, Sl, STh, STl,
                                Sh + (size_t)2 * NN * NN,
                                Sl + (size_t)2 * NN * NN);
  for (int i = 0; i < 4; i++) {
    k_padWt<<<blocks(128 * wKTa[i]), 256, 0, stream>>>(
        Wsrc[2 * i], Wrh[i], Wrl[i], wIndim[i], wDp[i], wKTa[i], 128);
    k_padWtCand<<<blocks(64 * wKTa[i]), 256, 0, stream>>>(
        Wsrc[2 * i + 1], Wch[i], Wcl[i], wIndim[i], wDp[i], wKTa[i], 64);
  }

  LayerH L[4];
  for (int i = 0; i < 4; i++) {
    bool lo = (wDp[i] == 72);
    L[i].YcRh = lo ? YcR0h : YcR1h; L[i].YcRl = lo ? YcR0l : YcR1l;
    L[i].YcCh = lo ? YcC0h : YcC1h; L[i].YcCl = lo ? YcC0l : YcC1l;
    L[i].hh = lo ? h0h : h1h; L[i].hl = lo ? h0l : h1l;
    L[i].ru = lo ? ru0 : ru1;
    L[i].Wrh = Wrh[i]; L[i].Wrl = Wrl[i]; L[i].Wch = Wch[i]; L[i].Wcl = Wcl[i];
    L[i].br = bias[2 * i]; L[i].bc = bias[2 * i + 1];
    L[i].indim = wIndim[i];
    L[i].CW = wDp[i]; L[i].KTa = wKTa[i]; L[i].STR = wKTa[i] + 64;
    L[i].nfull = lo ? 576 : 512;
  }

  auto prepSeg = [&](LayerH& Y, const float* inp, const float* st) {
    return PrepSeg{inp, st, Y.YcRh, Y.YcRl, Y.hh, Y.hl, Y.indim, Y.CW, Y.STR, BB * Y.CW};
  };
  auto dRuSeg = [&](LayerH& Y) {
    return DiffSeg{Y.YcRh, Y.YcRl, Y.hh, Y.hl, Y.nfull};
  };
  auto dCdSeg = [&](LayerH& Y) {
    return DiffSeg{Y.YcCh, Y.YcCl, Y.hh, Y.hl, 512};
  };
  auto ruSeg = [&](LayerH& Y, const float* stold) {
    return G3RuSeg{Y.hh, Y.hl, Y.Wrh, Y.Wrl, Y.br, stold, Y.ru,
                   Y.YcCh, Y.YcCl, Y.hh, Y.hl, Y.KTa, Y.STR, NB / 64};
  };
  auto cdSeg = [&](LayerH& Y, const float* stold, float* stout,
                   const float* ow, const float* ob, int t) {
    G3CdSeg g{};
    g.Ah = Y.hh; g.Al = Y.hl; g.Bh = Y.Wch; g.Bl = Y.Wcl;
    g.bias = Y.bc; g.ru = Y.ru; g.stold = stold; g.stout = stout;
    g.ow = ow; g.ob = ob; g.outg = out; g.decin = decin;
    g.t = t; g.KTa = Y.KTa; g.STR = Y.STR; g.nblk = NB / 64;
    return g;
  };

  auto cell72 = [&](LayerH& Y, const float* inp, const float* stold, float* stout) {
    PrepSeg p = prepSeg(Y, inp, stold);
    k_prepM<<<p.nblk, 256, 0, stream>>>(p, p);
    DiffSeg dr = dRuSeg(Y);
    k_diffM<0, -1><<<dr.nblk, 256, 0, stream>>>(dr, dr, Sh);
    G3RuSeg gr = ruSeg(Y, stold);
    k_g3ru<<<gr.nblk, 512, 0, stream>>>(gr, gr);
    DiffSeg dc = dCdSeg(Y);
    k_diffM<2, -1><<<dc.nblk, 256, 0, stream>>>(dc, dc, Sh);
    G3CdSeg gc = cdSeg(Y, stold, stout, nullptr, nullptr, 0);
    k_g3cd<<<gc.nblk, 256, 0, stream>>>(gc, gc);
  };
  auto cell128 = [&](LayerH& Y, const float* inp, const float* stold, float* stout) {
    PrepSeg p = prepSeg(Y, inp, stold);
    k_prepM<<<p.nblk, 256, 0, stream>>>(p, p);
    DiffSeg dr = dRuSeg(Y);
    k_diffM<1, -1><<<dr.nblk, 256, 0, stream>>>(dr, dr, Sh);
    G3RuSeg gr = ruSeg(Y, stold);
    k_g3ru<<<gr.nblk, 512, 0, stream>>>(gr, gr);
    DiffSeg dc = dCdSeg(Y);
    k_diffM<3, -1><<<dc.nblk, 256, 0, stream>>>(dc, dc, Sh);
    G3CdSeg gc = cdSeg(Y, stold, stout, nullptr, nullptr, 0);
    k_g3cd<<<gc.nblk, 256, 0, stream>>>(gc, gc);
  };

  float* P[2] = {P0, P1};

  // ---- encoder: pipelined l0(t) ∥ l1(t-1) ----
  cell72(L[0], xin, P1, P0);
  for (int t = 1; t < TT; t++) {
    const float* Pold = P[(t - 1) & 1];
    float* Pnew = P[t & 1];
    PrepSeg p0 = prepSeg(L[0], xin + (size_t)t * NB * 2, Pold);
    PrepSeg p1 = prepSeg(L[1], Pold, st1);
    k_prepM<<<p0.nblk + p1.nblk, 256, 0, stream>>>(p0, p1);
    DiffSeg dr0 = dRuSeg(L[0]), dr1 = dRuSeg(L[1]);
    k_diffM<0, 1><<<dr0.nblk + dr1.nblk, 256, 0, stream>>>(dr0, dr1, Sh);
    G3RuSeg gr0 = ruSeg(L[0], Pold), gr1 = ruSeg(L[1], st1);
    k_g3ru<<<gr0.nblk + gr1.nblk, 512, 0, stream>>>(gr0, gr1);
    DiffSeg dc0 = dCdSeg(L[0]), dc1 = dCdSeg(L[1]);
    k_diffM<2, 3><<<dc0.nblk + dc1.nblk, 256, 0, stream>>>(dc0, dc1, Sh);
    G3CdSeg gc0 = cdSeg(L[0], Pold, Pnew, nullptr, nullptr, 0);
    G3CdSeg gc1 = cdSeg(L[1], st1, st1, nullptr, nullptr, 0);
    k_g3cd<<<gc0.nblk + gc1.nblk, 256, 0, stream>>>(gc0, gc1);
  }
  cell128(L[1], P[1], st1, st1);

  // ---- decoder: sequential, prep fused into g3cd epilogues ----
  {
    PrepSeg pd0 = prepSeg(L[2], decin, P1);
    PrepSeg pd1 = prepSeg(L[3], P1, st1);
    k_prepM<<<pd0.nblk + pd1.nblk, 256, 0, stream>>>(pd0, pd1);
  }
  for (int t = 0; t < TT; t++) {
    DiffSeg dr0 = dRuSeg(L[2]);
    k_diffM<0, -1><<<dr0.nblk, 256, 0, stream>>>(dr0, dr0, Sh);
    G3RuSeg gr0 = ruSeg(L[2], P1);
    k_g3ru<<<gr0.nblk, 512, 0, stream>>>(gr0, gr0);
    DiffSeg dc0 = dCdSeg(L[2]);
    k_diffM<2, -1><<<dc0.nblk, 256, 0, stream>>>(dc0, dc0, Sh);
    G3CdSeg g0 = cdSeg(L[2], P1, P1, nullptr, nullptr, 0);
    g0.yAh = L[2].YcRh; g0.yAl = L[2].YcRl; g0.hAh = L[2].hh; g0.hAl = L[2].hl;
    g0.cwA = 72; g0.baseA = 0; g0.strA = 448;
    g0.yBh = L[3].YcRh; g0.yBl = L[3].YcRl; g0.hBh = L[3].hh; g0.hBl = L[3].hl;
    g0.cwB = 128; g0.baseB = 64; g0.strB = 704;
    k_g3cd<<<g0.nblk, 256, 0, stream>>>(g0, g0);
    DiffSeg dr1 = dRuSeg(L[3]);
    k_diffM<1, -1><<<dr1.nblk, 256, 0, stream>>>(dr1, dr1, Sh);
    G3RuSeg gr1 = ruSeg(L[3], st1);
    k_g3ru<<<gr1.nblk, 512, 0, stream>>>(gr1, gr1);
    DiffSeg dc1 = dCdSeg(L[3]);
    k_diffM<3, -1><<<dc1.nblk, 256, 0, stream>>>(dc1, dc1, Sh);
    G3CdSeg g1 = cdSeg(L[3], st1, st1, outW, outB, t);
    g1.yAh = L[3].YcRh; g1.yAl = L[3].YcRl; g1.hAh = L[3].hh; g1.hAl = L[3].hl;
    g1.cwA = 128; g1.baseA = 0; g1.strA = 704;
    g1.yPh = L[2].YcRh; g1.yPl = L[2].YcRl; g1.hPh = L[2].hh; g1.hPl = L[2].hl;
    g1.cwP = 72; g1.baseP = 64; g1.strP = 448;
    k_g3cd<<<g1.nblk, 256, 0, stream>>>(g1, g1);
  }
}

// Round 15
// 6638.754 us; speedup vs baseline: 1.1365x; 1.0194x over previous
//
#include <hip/hip_runtime.h>
#include <math.h>

// DCRNN on MI355X — round 15: R14 + encoder prep fully fused into g3cd
// epilogues (gc0 writes l0-state + l1-inp cols; gc1 writes l1-state + next-t
// xin cols), k_init1 seeds l1 state-zero cols once. Eliminates 12 prepM
// launches. Values bit-identical: absmax must stay exactly 6.103516e-05.

#define NN 1024
#define BB 16
#define TT 12
#define HH 64
#define NB (NN*BB)      // 16384

typedef unsigned short u16;
typedef unsigned int u32;
typedef __attribute__((ext_vector_type(8))) short sv8;
typedef __attribute__((ext_vector_type(4))) float f32x4;
typedef __attribute__((ext_vector_type(16))) float f32x16;

__device__ __forceinline__ void gload16(const void* g, void* l) {
  __builtin_amdgcn_global_load_lds(
      (const __attribute__((address_space(1))) void*)(unsigned long long)(g),
      (__attribute__((address_space(3))) void*)(l), 16, 0, 0);
}

#define WAIT_BAR(N) asm volatile("s_waitcnt vmcnt(" #N ")\n\ts_barrier" ::: "memory")
#define BAR() asm volatile("s_barrier" ::: "memory")

template<int NX, int NY, int NZ>
__device__ __forceinline__ void xcdmap(int bid, int& x, int& y, int& z) {
  constexpr int ZREP = 8 / NZ;
  constexpr int YH = NY / ZREP;
  int chunk = bid & 7, pos = bid >> 3;
  z = chunk / ZREP;
  int yh = chunk % ZREP;
  x = pos % NX;
  y = yh * YH + pos / NX;
}

__device__ __forceinline__ int swz(int row, int g) {
  int rp = row >> 1;
  int j = ((row & 1) << 2) | g;
  return (rp << 3) | (j ^ (rp & 7));
}

__device__ __forceinline__ u16 bf16_rne(float x) {
  u32 u = __float_as_uint(x);
  return (u16)((u + 0x7FFFu + ((u >> 16) & 1u)) >> 16);
}
__device__ __forceinline__ void split2(float x, u16& h, u16& l) {
  h = bf16_rne(x);
  float hf = __uint_as_float(((u32)h) << 16);
  l = bf16_rne(x - hf);
}

__global__ __launch_bounds__(256) void k_zero(float* p, int n) {
  int i = blockIdx.x * 256 + threadIdx.x;
  if (i < n) p[i] = 0.f;
}

// zero l1 state cols of Yc1 and h1 (hi+lo) — initial st1 = 0 for encoder t=1
__global__ __launch_bounds__(256) void k_init1(u16* __restrict__ ych, u16* __restrict__ ycl,
                                               u16* __restrict__ hh, u16* __restrict__ hl) {
  int idx = blockIdx.x * 256 + threadIdx.x;   // 16*64*1024
  if (idx >= 16 * 64 * NN) return;
  int n = idx & (NN - 1);
  int t = idx >> 10;
  int b = t >> 6, d = t & 63;
  ych[(size_t)(b * 128 + d) * NN + n] = 0;
  ycl[(size_t)(b * 128 + d) * NN + n] = 0;
  int nb = (n << 4) + b;
  hh[(size_t)nb * 704 + d] = 0;
  hl[(size_t)nb * 704 + d] = 0;
}

__global__ __launch_bounds__(256) void k_transpose_in(const float* __restrict__ in,
                                                      float* __restrict__ xt) {
  int idx = blockIdx.x * 256 + threadIdx.x;
  if (idx >= BB * TT * NN * 2) return;
  int i = idx & 1;
  int n = (idx >> 1) & (NN - 1);
  int bt = idx >> 11;
  int t = bt % TT, b = bt / TT;
  xt[(size_t)t * (NB * 2) + (size_t)(n * BB + b) * 2 + i] = in[idx];
}

__global__ __launch_bounds__(256) void k_splitS(const float* __restrict__ s,
                                                u16* __restrict__ sh, u16* __restrict__ sl) {
  int idx = blockIdx.x * 256 + threadIdx.x;
  if (idx >= 2 * NN * NN) return;
  u16 h, l; split2(s[idx], h, l);
  sh[idx] = h; sl[idx] = l;
}

__global__ __launch_bounds__(256) void k_transpS(const u16* __restrict__ sh,
        const u16* __restrict__ sl, u16* __restrict__ sth, u16* __restrict__ stl) {
  int idx = blockIdx.x * 256 + threadIdx.x;
  if (idx >= 2 * NN * NN) return;
  int j = idx & (NN - 1);
  int k = (idx >> 10) & (NN - 1);
  int z = idx >> 20;
  size_t src = ((size_t)z << 20) | ((size_t)j << 10) | (size_t)k;
  sth[idx] = sh[src];
  stl[idx] = sl[src];
}

__global__ __launch_bounds__(256) void k_padWt(const float* __restrict__ W,
        u16* __restrict__ Wth, u16* __restrict__ Wtl,
        int indim, int Dp, int KTa, int dout) {
  int idx = blockIdx.x * 256 + threadIdx.x;
  if (idx >= dout * KTa) return;
  int kk = idx % KTa, o = idx / KTa;
  int blk = kk / Dp, d = kk - blk * Dp;
  int Dreal = indim + 64;
  float v = 0.f;
  if (blk < 5) {
    int dorig = -1;
    if (d < 64) dorig = indim + d;
    else if (d - 64 < indim) dorig = d - 64;
    if (dorig >= 0) v = W[(size_t)(blk * Dreal + dorig) * dout + o];
  }
  u16 h, l; split2(v, h, l);
  Wth[idx] = h; Wtl[idx] = l;
}

__global__ __launch_bounds__(256) void k_padWtCand(const float* __restrict__ W,
        u16* __restrict__ Wth, u16* __restrict__ Wtl,
        int indim, int Dp, int KTa, int dout) {
  int idx = blockIdx.x * 256 + threadIdx.x;
  if (idx >= dout * KTa) return;
  int kk = idx % KTa, o = idx / KTa;
  int c = 64 + kk;
  int Dreal = indim + 64;
  float v = 0.f;
  if (c >= KTa) {
    int d = c - KTa;
    v = W[(size_t)(indim + d) * dout + o];
  } else {
    int blk = c / Dp, d = c - blk * Dp;
    if (blk == 0) {
      int di = d - 64;
      if (di < indim) v = W[(size_t)di * dout + o];
    } else {
      if (d < 64) v = W[(size_t)(blk * Dreal + indim + d) * dout + o];
      else if (d - 64 < indim) v = W[(size_t)(blk * Dreal + (d - 64)) * dout + o];
    }
  }
  u16 h, l; split2(v, h, l);
  Wth[idx] = h; Wtl[idx] = l;
}

struct PrepSeg {
  const float *inp, *st;
  u16 *ych, *ycl, *hh, *hl;
  int indim, CW, STR, nblk;
};
__global__ __launch_bounds__(256) void k_prepM(PrepSeg s0, PrepSeg s1) {
  const bool first = (int)blockIdx.x < s0.nblk;
  const PrepSeg s = first ? s0 : s1;
  const int c = first ? blockIdx.x : blockIdx.x - s0.nblk;
  int n0 = threadIdx.x << 2;
  int b = c / s.CW, d = c - b * s.CW;
  u16 h4[4], l4[4];
  #pragma unroll
  for (int r = 0; r < 4; r++) {
    int nb = ((n0 + r) << 4) + b;
    float v = 0.f;
    if (d < 64) v = s.st[(size_t)nb * HH + d];
    else if (d - 64 < s.indim) v = s.inp[(size_t)nb * s.indim + (d - 64)];
    split2(v, h4[r], l4[r]);
    s.hh[(size_t)nb * s.STR + d] = h4[r];
    s.hl[(size_t)nb * s.STR + d] = l4[r];
  }
  uint2 ph, pl;
  ph.x = (u32)h4[0] | ((u32)h4[1] << 16); ph.y = (u32)h4[2] | ((u32)h4[3] << 16);
  pl.x = (u32)l4[0] | ((u32)l4[1] << 16); pl.y = (u32)l4[2] | ((u32)l4[3] << 16);
  *(uint2*)&s.ych[(size_t)c * NN + n0] = ph;
  *(uint2*)&s.ycl[(size_t)c * NN + n0] = pl;
}

struct StageMap {
  int row1, g1, row2, g2;
  __device__ StageMap(int tid) {
    int rp = tid >> 3, jx = (tid & 7) ^ (rp & 7);
    row1 = (rp << 1) | (jx >> 2); g1 = jx & 3;
    int s = tid + 256; rp = s >> 3; jx = (s & 7) ^ (rp & 7);
    row2 = (rp << 1) | (jx >> 2); g2 = jx & 3;
  }
};

// ---------- S^2 (setup, runs once; full 3-term precision) ----------
__global__ __launch_bounds__(256) void k_sq(
    const u16* __restrict__ Sh, const u16* __restrict__ Sl,
    const u16* __restrict__ STh, const u16* __restrict__ STl,
    u16* __restrict__ Oh, u16* __restrict__ Ol)
{
  __shared__ __attribute__((aligned(16))) u16 lA[2][2][4096];
  __shared__ __attribute__((aligned(16))) u16 lB[2][2][4096];
  const int tid = threadIdx.x;
  const int lane = tid & 63, wave = tid >> 6;
  int bx, by, z;
  xcdmap<8, 8, 2>(blockIdx.x, bx, by, z);
  const int a0 = bx << 7, b0 = by << 7;
  const int wc0 = (wave & 1) << 6, wn0 = (wave >> 1) << 6;
  StageMap sm(tid);
  const u16* pa1h = Sh + (size_t)z * NN * NN + (size_t)(a0 + sm.row1) * NN + sm.g1 * 8;
  const u16* pa2h = Sh + (size_t)z * NN * NN + (size_t)(a0 + sm.row2) * NN + sm.g2 * 8;
  const u16* pa1l = Sl + (size_t)z * NN * NN + (size_t)(a0 + sm.row1) * NN + sm.g1 * 8;
  const u16* pa2l = Sl + (size_t)z * NN * NN + (size_t)(a0 + sm.row2) * NN + sm.g2 * 8;
  const u16* pb1h = STh + (size_t)z * NN * NN + (size_t)(b0 + sm.row1) * NN + sm.g1 * 8;
  const u16* pb2h = STh + (size_t)z * NN * NN + (size_t)(b0 + sm.row2) * NN + sm.g2 * 8;
  const u16* pb1l = STl + (size_t)z * NN * NN + (size_t)(b0 + sm.row1) * NN + sm.g1 * 8;
  const u16* pb2l = STl + (size_t)z * NN * NN + (size_t)(b0 + sm.row2) * NN + sm.g2 * 8;

  f32x16 acc[2][2];
  #pragma unroll
  for (int i = 0; i < 2; i++)
    #pragma unroll
    for (int j = 0; j < 2; j++)
      #pragma unroll
      for (int e = 0; e < 16; e++) acc[i][j][e] = 0.f;

  auto stage = [&](int buf, int k0) {
    gload16(pa1h + k0, &lA[buf][0][tid * 8]);
    gload16(pa2h + k0, &lA[buf][0][tid * 8 + 2048]);
    gload16(pa1l + k0, &lA[buf][1][tid * 8]);
    gload16(pa2l + k0, &lA[buf][1][tid * 8 + 2048]);
    gload16(pb1h + k0, &lB[buf][0][tid * 8]);
    gload16(pb2h + k0, &lB[buf][0][tid * 8 + 2048]);
    gload16(pb1l + k0, &lB[buf][1][tid * 8]);
    gload16(pb2l + k0, &lB[buf][1][tid * 8 + 2048]);
  };
  stage(0, 0);
  __syncthreads();
  int cur = 0;
  for (int kt = 0; kt < 32; kt++) {
    if (kt < 31) stage(cur ^ 1, (kt + 1) * 32);
    #pragma unroll
    for (int kh = 0; kh < 2; kh++) {
      sv8 vah[2], vaL[2], vbh[2], vbL[2];
      int gsel = (kh << 1) | (lane >> 5);
      #pragma unroll
      for (int f = 0; f < 2; f++) {
        int offa = swz(wc0 + f * 32 + (lane & 31), gsel) * 8;
        vah[f] = *(const sv8*)&lA[cur][0][offa];
        vaL[f] = *(const sv8*)&lA[cur][1][offa];
        int offb = swz(wn0 + f * 32 + (lane & 31), gsel) * 8;
        vbh[f] = *(const sv8*)&lB[cur][0][offb];
        vbL[f] = *(const sv8*)&lB[cur][1][offb];
      }
      #pragma unroll
      for (int fm = 0; fm < 2; fm++)
        #pragma unroll
        for (int fn = 0; fn < 2; fn++) {
          acc[fm][fn] = __builtin_amdgcn_mfma_f32_32x32x16_bf16(vah[fm], vbh[fn], acc[fm][fn], 0, 0, 0);
          acc[fm][fn] = __builtin_amdgcn_mfma_f32_32x32x16_bf16(vah[fm], vbL[fn], acc[fm][fn], 0, 0, 0);
          acc[fm][fn] = __builtin_amdgcn_mfma_f32_32x32x16_bf16(vaL[fm], vbh[fn], acc[fm][fn], 0, 0, 0);
        }
    }
    __syncthreads();
    cur ^= 1;
  }
  u16* oh = Oh + (size_t)z * NN * NN;
  u16* ol = Ol + (size_t)z * NN * NN;
  #pragma unroll
  for (int fm = 0; fm < 2; fm++)
    #pragma unroll
    for (int q = 0; q < 4; q++) {
      int m4 = a0 + wc0 + fm * 32 + q * 8 + ((lane >> 5) << 2);
      #pragma unroll
      for (int fn = 0; fn < 2; fn++) {
        int kc = b0 + wn0 + fn * 32 + (lane & 31);
        #pragma unroll
        for (int r = 0; r < 4; r++) {
          u16 hi, lo; split2(acc[fm][fn][q * 4 + r], hi, lo);
          oh[(size_t)(m4 + r) * NN + kc] = hi;
          ol[(size_t)(m4 + r) * NN + kc] = lo;
        }
      }
    }
}

// ---------- diffusion (BK=32, counted vmcnt, 2-term, coalesced epilogue) ----------
struct DiffSeg { const u16 *Ah, *Al; u16 *hh, *hl; int nblk; };

constexpr int bn_of(int V) { return (V == 1) ? 128 : 64; }

template<int V>
__device__ __forceinline__ void diffuse_body(int bid, const DiffSeg s,
    const u16* __restrict__ Sh, u16* lds)
{
  constexpr int BN  = bn_of(V);
  constexpr int DP  = (V == 0 || V == 2) ? 72 : 128;
  constexpr int KTA = (V == 0 || V == 2) ? 384 : 640;
  constexpr int STR = KTA + 64;
  constexpr int CW  = (V == 0) ? 72 : ((V == 1) ? 128 : 64);
  constexpr int NX  = (V == 0) ? 9 : ((V == 1) ? 16 : 8);
  constexpr int NY  = (BN == 128) ? 8 : 16;
  constexpr int FN  = BN / 64;

  u16* sA = lds;
  u16* sB = lds + 4 * 4096;
  const int tid = threadIdx.x;
  const int lane = tid & 63, wave = tid >> 6;
  int bx, by, z;
  xcdmap<NX, NY, 4>(bid, bx, by, z);
  const int a0 = bx << 7;
  const int b0 = by * BN;
  const int wc0 = (wave & 1) << 6;
  const int wn0 = (wave >> 1) * (BN / 2);
  StageMap sm(tid);
  const u16* pa1h = s.Ah + (size_t)(a0 + sm.row1) * NN + sm.g1 * 8;
  const u16* pa2h = s.Ah + (size_t)(a0 + sm.row2) * NN + sm.g2 * 8;
  const u16* pa1l = s.Al + (size_t)(a0 + sm.row1) * NN + sm.g1 * 8;
  const u16* pa2l = s.Al + (size_t)(a0 + sm.row2) * NN + sm.g2 * 8;
  const u16* pb1h = Sh + (size_t)z * NN * NN + (size_t)(b0 + sm.row1) * NN + sm.g1 * 8;
  const u16* pb2h = Sh + (size_t)z * NN * NN + (size_t)(b0 + sm.row2) * NN + sm.g2 * 8;

  f32x16 acc[2][FN];
  #pragma unroll
  for (int i = 0; i < 2; i++)
    #pragma unroll
    for (int j = 0; j < FN; j++)
      #pragma unroll
      for (int e = 0; e < 16; e++) acc[i][j][e] = 0.f;

  auto stage = [&](int buf, int k0) {
    gload16(pa1h + k0, sA + (buf * 2 + 0) * 4096 + tid * 8);
    gload16(pa1l + k0, sA + (buf * 2 + 1) * 4096 + tid * 8);
    gload16(pa2h + k0, sA + (buf * 2 + 0) * 4096 + tid * 8 + 2048);
    gload16(pa2l + k0, sA + (buf * 2 + 1) * 4096 + tid * 8 + 2048);
    gload16(pb1h + k0, sB + buf * (BN * 32) + tid * 8);
    if constexpr (BN == 128)
      gload16(pb2h + k0, sB + buf * (BN * 32) + tid * 8 + 2048);
  };
  stage(0, 0);
  int cur = 0;
  for (int kt = 0; kt < 32; kt++) {
    if (kt < 31) {
      stage(cur ^ 1, (kt + 1) * 32);
      if constexpr (BN == 128) { WAIT_BAR(6); } else { WAIT_BAR(5); }
    } else {
      WAIT_BAR(0);
    }
    #pragma unroll
    for (int kh = 0; kh < 2; kh++) {
      sv8 vah[2], vaL[2], vbh[FN];
      int gsel = (kh << 1) | (lane >> 5);
      #pragma unroll
      for (int f = 0; f < 2; f++) {
        int offa = swz(wc0 + f * 32 + (lane & 31), gsel) * 8;
        vah[f] = *(const sv8*)(sA + (cur * 2 + 0) * 4096 + offa);
        vaL[f] = *(const sv8*)(sA + (cur * 2 + 1) * 4096 + offa);
      }
      #pragma unroll
      for (int f = 0; f < FN; f++) {
        int offb = swz(wn0 + f * 32 + (lane & 31), gsel) * 8;
        vbh[f] = *(const sv8*)(sB + cur * (BN * 32) + offb);
      }
      #pragma unroll
      for (int fm = 0; fm < 2; fm++)
        #pragma unroll
        for (int fn = 0; fn < FN; fn++) {
          acc[fm][fn] = __builtin_amdgcn_mfma_f32_32x32x16_bf16(vah[fm], vbh[fn], acc[fm][fn], 0, 0, 0);
          acc[fm][fn] = __builtin_amdgcn_mfma_f32_32x32x16_bf16(vaL[fm], vbh[fn], acc[fm][fn], 0, 0, 0);
        }
    }
    BAR();
    cur ^= 1;
  }

  // ---- coalesced epilogue: LDS transpose [m][132], two passes (hi, lo) ----
  const int blkoff = (1 + ((z & 1) << 1) + (z >> 1)) * DP;
  u16* const dsts[2] = {s.hh, s.hl};
  #pragma unroll
  for (int p = 0; p < 2; p++) {
    #pragma unroll
    for (int fm = 0; fm < 2; fm++)
      #pragma unroll
      for (int q = 0; q < 4; q++) {
        int cl = wc0 + fm * 32 + q * 8 + ((lane >> 5) << 2);
        #pragma unroll
        for (int fn = 0; fn < FN; fn++) {
          int ml = wn0 + fn * 32 + (lane & 31);
          u16 v4[4];
          #pragma unroll
          for (int r = 0; r < 4; r++) {
            u16 hi, lo; split2(acc[fm][fn][q * 4 + r], hi, lo);
            v4[r] = p ? lo : hi;
          }
          uint2 pk;
          pk.x = (u32)v4[0] | ((u32)v4[1] << 16);
          pk.y = (u32)v4[2] | ((u32)v4[3] << 16);
          *(uint2*)&lds[ml * 132 + cl] = pk;
        }
      }
    __syncthreads();
    u16* dst = dsts[p];
    #pragma unroll
    for (int i = 0; i < BN * 32 / 256; i++) {
      int w = tid + (i << 8);
      int ml = w >> 5, c4 = (w & 31) << 2;
      uint2 pk = *(uint2*)&lds[ml * 132 + c4];
      int cg = a0 + c4;
      int bq = cg / CW, dq = cg - bq * CW;
      int nb = ((b0 + ml) << 4) + bq;
      *(uint2*)&dst[(size_t)nb * STR + blkoff + dq] = pk;
    }
    __syncthreads();
  }
}

template<int VA, int VB>
__global__ __launch_bounds__(256) void k_diffM(DiffSeg s0, DiffSeg s1,
    const u16* __restrict__ Sh) {
  constexpr int BNA = bn_of(VA);
  constexpr int BNB = (VB >= 0) ? bn_of(VB) : 64;
  constexpr int MB = BNA > BNB ? BNA : BNB;
  constexpr int STG = 4 * 4096 + 2 * MB * 32;
  constexpr int TRN = MB * 132;
  constexpr int TOT = STG > TRN ? STG : TRN;
  __shared__ __attribute__((aligned(16))) u16 lds[TOT];
  if ((int)blockIdx.x < s0.nblk) {
    diffuse_body<VA>(blockIdx.x, s0, Sh, lds);
  } else {
    if constexpr (VB >= 0)
      diffuse_body<VB>(blockIdx.x - s0.nblk, s1, Sh, lds);
  }
}

// ---------- gemm-ru (dbuf, counted vmcnt NL=3) + fused cand-prep ----------
struct G3RuSeg {
  const u16 *Ah, *Al, *Bh, *Bl;
  const float *bias, *stold;
  float *ru;
  u16 *ych, *ycl, *hh, *hl;
  int KTa, STR, nblk;
};
__global__ __launch_bounds__(512) void k_g3ru(G3RuSeg s0, G3RuSeg s1) {
  __shared__ __attribute__((aligned(16))) u16 lAh[2][2048];
  __shared__ __attribute__((aligned(16))) u16 lAl[2][2048];
  __shared__ __attribute__((aligned(16))) u16 lBh[2][4096];
  __shared__ __attribute__((aligned(16))) u16 lBl[2][4096];
  const bool first = (int)blockIdx.x < s0.nblk;
  const G3RuSeg s = first ? s0 : s1;
  const int bid = first ? blockIdx.x : blockIdx.x - s0.nblk;
  const int tid = threadIdx.x;
  const int lane = tid & 63, wave = tid >> 6;
  const int a0 = bid << 6;
  const int wr0 = (wave & 1) << 5;
  const int wn0 = (wave >> 1) << 5;
  const int gw = lane >> 4, rsel = lane & 15;
  const int sAi = tid & 255;
  int rp = sAi >> 3, jx = (sAi & 7) ^ (rp & 7);
  const int rowA = (rp << 1) | (jx >> 2), gAc = jx & 3;
  rp = tid >> 3; jx = (tid & 7) ^ (rp & 7);
  const int rowB = (rp << 1) | (jx >> 2), gBc = jx & 3;

  f32x4 acc[2][2];
  #pragma unroll
  for (int i = 0; i < 2; i++)
    #pragma unroll
    for (int j = 0; j < 2; j++) acc[i][j] = (f32x4){0.f, 0.f, 0.f, 0.f};

  auto stg = [&](int buf, int k0) {
    if (tid < 256) gload16(s.Ah + (size_t)(a0 + rowA) * s.STR + k0 + gAc * 8, &lAh[buf][sAi * 8]);
    else           gload16(s.Al + (size_t)(a0 + rowA) * s.STR + k0 + gAc * 8, &lAl[buf][sAi * 8]);
    gload16(s.Bh + (size_t)rowB * s.KTa + k0 + gBc * 8, &lBh[buf][tid * 8]);
    gload16(s.Bl + (size_t)rowB * s.KTa + k0 + gBc * 8, &lBl[buf][tid * 8]);
  };
  const int NI = s.KTa >> 5;
  stg(0, 0);
  int cur = 0;
  for (int i = 0; i < NI; i++) {
    if (i < NI - 1) {
      stg(cur ^ 1, (i + 1) * 32);
      WAIT_BAR(3);
    } else {
      WAIT_BAR(0);
    }
    sv8 vah[2], vaL[2], vbh[2], vbL[2];
    #pragma unroll
    for (int f = 0; f < 2; f++) {
      int offa = swz(wr0 + f * 16 + rsel, gw) * 8;
      vah[f] = *(const sv8*)&lAh[cur][offa];
      vaL[f] = *(const sv8*)&lAl[cur][offa];
      int offb = swz(wn0 + f * 16 + rsel, gw) * 8;
      vbh[f] = *(const sv8*)&lBh[cur][offb];
      vbL[f] = *(const sv8*)&lBl[cur][offb];
    }
    #pragma unroll
    for (int fm = 0; fm < 2; fm++)
      #pragma unroll
      for (int fn = 0; fn < 2; fn++) {
        acc[fm][fn] = __builtin_amdgcn_mfma_f32_16x16x32_bf16(vah[fm], vbh[fn], acc[fm][fn], 0, 0, 0);
        acc[fm][fn] = __builtin_amdgcn_mfma_f32_16x16x32_bf16(vah[fm], vbL[fn], acc[fm][fn], 0, 0, 0);
        acc[fm][fn] = __builtin_amdgcn_mfma_f32_16x16x32_bf16(vaL[fm], vbh[fn], acc[fm][fn], 0, 0, 0);
      }
    BAR();
    cur ^= 1;
  }

  #pragma unroll
  for (int fm = 0; fm < 2; fm++) {
    #pragma unroll
    for (int r = 0; r < 4; r++) {
      int nb = a0 + wr0 + fm * 16 + ((lane >> 4) << 2) + r;
      #pragma unroll
      for (int fn = 0; fn < 2; fn++) {
        int o = wn0 + fn * 16 + rsel;
        float v = acc[fm][fn][r] + s.bias[o];
        float sig = 1.f / (1.f + expf(-v));
        s.ru[(size_t)nb * 128 + o] = sig;
        if (o < 64) {
          float rv = sig * s.stold[(size_t)nb * HH + o];
          u16 hi, lo; split2(rv, hi, lo);
          int cc = ((nb & 15) << 6) + o;
          s.ych[(size_t)cc * NN + (nb >> 4)] = hi;
          s.ycl[(size_t)cc * NN + (nb >> 4)] = lo;
          s.hh[(size_t)nb * s.STR + s.KTa + o] = hi;
          s.hl[(size_t)nb * s.STR + s.KTa + o] = lo;
        }
      }
    }
  }
}

// ---------- gemm-cand (dbuf, NL=4) + fused next-cell prep + projection ----------
struct G3CdSeg {
  const u16 *Ah, *Al, *Bh, *Bl;
  const float *bias, *ru, *stold;
  float *stout;
  u16 *yAh, *yAl, *hAh, *hAl; int cwA, baseA, strA;
  u16 *yBh, *yBl, *hBh, *hBl; int cwB, baseB, strB;
  const float *ow, *ob;
  float *outg, *decin;
  u16 *yPh, *yPl, *hPh, *hPl; int cwP, baseP, strP;
  const float *xp;                 // encoder: next-t xin (2 cols at base 64 of l0)
  u16 *yXh, *yXl, *hXh, *hXl;
  int t, KTa, STR, nblk;
};
__global__ __launch_bounds__(256) void k_g3cd(G3CdSeg s0, G3CdSeg s1) {
  __shared__ __attribute__((aligned(16))) u16 lAh[2][2048];
  __shared__ __attribute__((aligned(16))) u16 lAl[2][2048];
  __shared__ __attribute__((aligned(16))) u16 lBh[2][2048];
  __shared__ __attribute__((aligned(16))) u16 lBl[2][2048];
  __shared__ float pst[64][65];
  const bool first = (int)blockIdx.x < s0.nblk;
  const G3CdSeg s = first ? s0 : s1;
  const int bid = first ? blockIdx.x : blockIdx.x - s0.nblk;
  const int tid = threadIdx.x;
  const int lane = tid & 63, wave = tid >> 6;
  const int a0 = bid << 6;
  const int wr0 = (wave & 1) << 5;
  const int wn0 = (wave >> 1) << 5;
  const int gw = lane >> 4, rsel = lane & 15;
  int rp = tid >> 3, jx = (tid & 7) ^ (rp & 7);
  const int rowA = (rp << 1) | (jx >> 2), gAc = jx & 3;

  f32x4 acc[2][2];
  #pragma unroll
  for (int i = 0; i < 2; i++)
    #pragma unroll
    for (int j = 0; j < 2; j++) acc[i][j] = (f32x4){0.f, 0.f, 0.f, 0.f};

  auto stg = [&](int buf, int k0) {
    gload16(s.Ah + (size_t)(a0 + rowA) * s.STR + 64 + k0 + gAc * 8, &lAh[buf][tid * 8]);
    gload16(s.Al + (size_t)(a0 + rowA) * s.STR + 64 + k0 + gAc * 8, &lAl[buf][tid * 8]);
    gload16(s.Bh + (size_t)rowA * s.KTa + k0 + gAc * 8, &lBh[buf][tid * 8]);
    gload16(s.Bl + (size_t)rowA * s.KTa + k0 + gAc * 8, &lBl[buf][tid * 8]);
  };
  const int NI = s.KTa >> 5;
  stg(0, 0);
  int cur = 0;
  for (int i = 0; i < NI; i++) {
    if (i < NI - 1) {
      stg(cur ^ 1, (i + 1) * 32);
      WAIT_BAR(4);
    } else {
      WAIT_BAR(0);
    }
    sv8 vah[2], vaL[2], vbh[2], vbL[2];
    #pragma unroll
    for (int f = 0; f < 2; f++) {
      int offa = swz(wr0 + f * 16 + rsel, gw) * 8;
      vah[f] = *(const sv8*)&lAh[cur][offa];
      vaL[f] = *(const sv8*)&lAl[cur][offa];
      int offb = swz(wn0 + f * 16 + rsel, gw) * 8;
      vbh[f] = *(const sv8*)&lBh[cur][offb];
      vbL[f] = *(const sv8*)&lBl[cur][offb];
    }
    #pragma unroll
    for (int fm = 0; fm < 2; fm++)
      #pragma unroll
      for (int fn = 0; fn < 2; fn++) {
        acc[fm][fn] = __builtin_amdgcn_mfma_f32_16x16x32_bf16(vah[fm], vbh[fn], acc[fm][fn], 0, 0, 0);
        acc[fm][fn] = __builtin_amdgcn_mfma_f32_16x16x32_bf16(vah[fm], vbL[fn], acc[fm][fn], 0, 0, 0);
        acc[fm][fn] = __builtin_amdgcn_mfma_f32_16x16x32_bf16(vaL[fm], vbh[fn], acc[fm][fn], 0, 0, 0);
      }
    BAR();
    cur ^= 1;
  }

  #pragma unroll
  for (int fm = 0; fm < 2; fm++) {
    #pragma unroll
    for (int r = 0; r < 4; r++) {
      int nb = a0 + wr0 + fm * 16 + ((lane >> 4) << 2) + r;
      #pragma unroll
      for (int fn = 0; fn < 2; fn++) {
        int o = wn0 + fn * 16 + rsel;
        float v = acc[fm][fn][r] + s.bias[o];
        float u = s.ru[(size_t)nb * 128 + 64 + o];
        float sold = s.stold[(size_t)nb * HH + o];
        float ns = u * sold + (1.f - u) * tanhf(v);
        s.stout[(size_t)nb * HH + o] = ns;
        int b = nb & 15, n = nb >> 4;
        if (s.yAh) {
          u16 hi, lo; split2(ns, hi, lo);
          int c = b * s.cwA + s.baseA + o;
          s.yAh[(size_t)c * NN + n] = hi;
          s.yAl[(size_t)c * NN + n] = lo;
          s.hAh[(size_t)nb * s.strA + s.baseA + o] = hi;
          s.hAl[(size_t)nb * s.strA + s.baseA + o] = lo;
        }
        if (s.yBh) {
          u16 hi, lo; split2(ns, hi, lo);
          int c = b * s.cwB + s.baseB + o;
          s.yBh[(size_t)c * NN + n] = hi;
          s.yBl[(size_t)c * NN + n] = lo;
          s.hBh[(size_t)nb * s.strB + s.baseB + o] = hi;
          s.hBl[(size_t)nb * s.strB + s.baseB + o] = lo;
        }
        if (s.ow) pst[nb - a0][o] = ns;
      }
    }
  }
  if (s.xp) {
    if (tid < 128) {
      int rloc = tid >> 1, d = tid & 1;
      int nb = a0 + rloc;
      float v = s.xp[(size_t)nb * 2 + d];
      u16 hi, lo; split2(v, hi, lo);
      int b = nb & 15, n = nb >> 4;
      int c = b * 72 + 64 + d;
      s.yXh[(size_t)c * NN + n] = hi;
      s.yXl[(size_t)c * NN + n] = lo;
      s.hXh[(size_t)nb * 448 + 64 + d] = hi;
      s.hXl[(size_t)nb * 448 + 64 + d] = lo;
    }
  }
  if (s.ow) {
    __syncthreads();
    if (tid < 64) {
      int nb = a0 + tid;
      float a2 = s.ob[0];
      #pragma unroll
      for (int o = 0; o < HH; o++) a2 += pst[tid][o] * s.ow[o];
      int n = nb >> 4, b = nb & 15;
      s.outg[((size_t)b * TT + s.t) * NN + n] = a2;
      s.decin[nb] = a2;
      if (s.yPh) {
        u16 hi, lo; split2(a2, hi, lo);
        int c = b * s.cwP + s.baseP;
        s.yPh[(size_t)c * NN + n] = hi;
        s.yPl[(size_t)c * NN + n] = lo;
        s.hPh[(size_t)nb * s.strP + s.baseP] = hi;
        s.hPl[(size_t)nb * s.strP + s.baseP] = lo;
      }
    }
  }
}

// ---------------- host ----------------
struct LayerH {
  u16 *YcRh, *YcRl, *YcCh, *YcCl, *hh, *hl;
  float *ru;
  u16 *Wrh, *Wrl, *Wch, *Wcl;
  const float *br, *bc;
  int indim, CW, KTa, STR, nfull;
};

extern "C" void kernel_launch(void* const* d_in, const int* in_sizes, int n_in,
                              void* d_out, int out_size, void* d_ws, size_t ws_size,
                              hipStream_t stream) {
  const float* inputs   = (const float*)d_in[0];
  const float* supports = (const float*)d_in[1];
  const float* Wsrc[8] = {(const float*)d_in[2], (const float*)d_in[4],
                          (const float*)d_in[6], (const float*)d_in[8],
                          (const float*)d_in[10], (const float*)d_in[12],
                          (const float*)d_in[14], (const float*)d_in[16]};
  const float* bias[8] = {(const float*)d_in[3], (const float*)d_in[5],
                          (const float*)d_in[7], (const float*)d_in[9],
                          (const float*)d_in[11], (const float*)d_in[13],
                          (const float*)d_in[15], (const float*)d_in[17]};
  const float* outW = (const float*)d_in[18];
  const float* outB = (const float*)d_in[19];
  float* out = (float*)d_out;

  char* cur = (char*)d_ws;
  auto alloc = [&](size_t bytes) -> char* {
    char* p = cur; cur += (bytes + 255) & ~(size_t)255; return p;
  };
  u16* Sh    = (u16*)alloc((size_t)4 * NN * NN * 2);
  u16* Sl    = (u16*)alloc((size_t)4 * NN * NN * 2);
  u16* YcR0h = (u16*)alloc((size_t)1152 * NN * 2);
  u16* YcR0l = (u16*)alloc((size_t)1152 * NN * 2);
  u16* YcR1h = (u16*)alloc((size_t)2048 * NN * 2);
  u16* YcR1l = (u16*)alloc((size_t)2048 * NN * 2);
  u16* h0h   = (u16*)alloc((size_t)NB * 448 * 2);
  u16* h0l   = (u16*)alloc((size_t)NB * 448 * 2);
  u16* h1h   = (u16*)alloc((size_t)NB * 704 * 2);
  u16* h1l   = (u16*)alloc((size_t)NB * 704 * 2);
  float* ru0 = (float*)alloc((size_t)NB * 128 * 4);
  float* ru1 = (float*)alloc((size_t)NB * 128 * 4);
  float* P0  = (float*)alloc((size_t)NB * HH * 4);
  float* P1  = (float*)alloc((size_t)NB * HH * 4);
  float* st1 = (float*)alloc((size_t)NB * HH * 4);
  float* decin = (float*)alloc((size_t)NB * 4);
  float* xin = (float*)alloc((size_t)TT * NB * 2 * 4);
  u16* STh = h1h;
  u16* STl = h1l;
  u16* YcC0h = YcR0h; u16* YcC0l = YcR0l;
  u16* YcC1h = YcR1h; u16* YcC1l = YcR1l;

  const int wKTa[4]  = {384, 640, 384, 640};
  const int wIndim[4]= {2, 64, 1, 64};
  const int wDp[4]   = {72, 128, 72, 128};
  u16 *Wrh[4], *Wrl[4], *Wch[4], *Wcl[4];
  for (int i = 0; i < 4; i++) {
    Wrh[i] = (u16*)alloc((size_t)128 * wKTa[i] * 2);
    Wrl[i] = (u16*)alloc((size_t)128 * wKTa[i] * 2);
    Wch[i] = (u16*)alloc((size_t)64 * wKTa[i] * 2);
    Wcl[i] = (u16*)alloc((size_t)64 * wKTa[i] * 2);
  }

  auto blocks = [](int n) { return (n + 255) / 256; };
  k_zero<<<blocks(NB * HH), 256, 0, stream>>>(P1, NB * HH);
  k_zero<<<blocks(NB * HH), 256, 0, stream>>>(st1, NB * HH);
  k_zero<<<blocks(NB), 256, 0, stream>>>(decin, NB);
  k_transpose_in<<<blocks(BB * TT * NN * 2), 256, 0, stream>>>(inputs, xin);
  k_splitS<<<blocks(2 * NN * NN), 256, 0, stream>>>(supports, Sh, Sl);
  k_transpS<<<blocks(2 * NN * NN), 256, 0, stream>>>(Sh, Sl, STh, STl);
  k_sq<<<128, 256, 0, stream>>>(Sh, Sl, STh, STl,
                                Sh + (size_t)2 * NN * NN,
                                Sl + (size_t)2 * NN * NN);
  k_init1<<<blocks(16 * 64 * NN), 256, 0, stream>>>(YcR1h, YcR1l, h1h, h1l);
  for (int i = 0; i < 4; i++) {
    k_padWt<<<blocks(128 * wKTa[i]), 256, 0, stream>>>(
        Wsrc[2 * i], Wrh[i], Wrl[i], wIndim[i], wDp[i], wKTa[i], 128);
    k_padWtCand<<<blocks(64 * wKTa[i]), 256, 0, stream>>>(
        Wsrc[2 * i + 1], Wch[i], Wcl[i], wIndim[i], wDp[i], wKTa[i], 64);
  }

  LayerH L[4];
  for (int i = 0; i < 4; i++) {
    bool lo = (wDp[i] == 72);
    L[i].YcRh = lo ? YcR0h : YcR1h; L[i].YcRl = lo ? YcR0l : YcR1l;
    L[i].YcCh = lo ? YcC0h : YcC1h; L[i].YcCl = lo ? YcC0l : YcC1l;
    L[i].hh = lo ? h0h : h1h; L[i].hl = lo ? h0l : h1l;
    L[i].ru = lo ? ru0 : ru1;
    L[i].Wrh = Wrh[i]; L[i].Wrl = Wrl[i]; L[i].Wch = Wch[i]; L[i].Wcl = Wcl[i];
    L[i].br = bias[2 * i]; L[i].bc = bias[2 * i + 1];
    L[i].indim = wIndim[i];
    L[i].CW = wDp[i]; L[i].KTa = wKTa[i]; L[i].STR = wKTa[i] + 64;
    L[i].nfull = lo ? 576 : 512;
  }

  auto prepSeg = [&](LayerH& Y, const float* inp, const float* st) {
    return PrepSeg{inp, st, Y.YcRh, Y.YcRl, Y.hh, Y.hl, Y.indim, Y.CW, Y.STR, BB * Y.CW};
  };
  auto dRuSeg = [&](LayerH& Y) {
    return DiffSeg{Y.YcRh, Y.YcRl, Y.hh, Y.hl, Y.nfull};
  };
  auto dCdSeg = [&](LayerH& Y) {
    return DiffSeg{Y.YcCh, Y.YcCl, Y.hh, Y.hl, 512};
  };
  auto ruSeg = [&](LayerH& Y, const float* stold) {
    return G3RuSeg{Y.hh, Y.hl, Y.Wrh, Y.Wrl, Y.br, stold, Y.ru,
                   Y.YcCh, Y.YcCl, Y.hh, Y.hl, Y.KTa, Y.STR, NB / 64};
  };
  auto cdSeg = [&](LayerH& Y, const float* stold, float* stout,
                   const float* ow, const float* ob, int t) {
    G3CdSeg g{};
    g.Ah = Y.hh; g.Al = Y.hl; g.Bh = Y.Wch; g.Bl = Y.Wcl;
    g.bias = Y.bc; g.ru = Y.ru; g.stold = stold; g.stout = stout;
    g.ow = ow; g.ob = ob; g.outg = out; g.decin = decin;
    g.t = t; g.KTa = Y.KTa; g.STR = Y.STR; g.nblk = NB / 64;
    return g;
  };
  // epilogue target helpers
  auto tgtA = [&](G3CdSeg& g, LayerH& Y, int base) {  // write ns as Y state/inp cols
    g.yAh = Y.YcRh; g.yAl = Y.YcRl; g.hAh = Y.hh; g.hAl = Y.hl;
    g.cwA = Y.CW; g.baseA = base; g.strA = Y.STR;
  };
  auto tgtB = [&](G3CdSeg& g, LayerH& Y, int base) {
    g.yBh = Y.YcRh; g.yBl = Y.YcRl; g.hBh = Y.hh; g.hBl = Y.hl;
    g.cwB = Y.CW; g.baseB = base; g.strB = Y.STR;
  };
  auto tgtX = [&](G3CdSeg& g, const float* xp) {       // encoder l0 xin cols
    g.xp = xp;
    g.yXh = L[0].YcRh; g.yXl = L[0].YcRl; g.hXh = L[0].hh; g.hXl = L[0].hl;
  };

  float* P[2] = {P0, P1};

  // ---- encoder t=0: l0 cell (prep kept), epilogue feeds t=1 ----
  {
    PrepSeg p = prepSeg(L[0], xin, P1);
    k_prepM<<<p.nblk, 256, 0, stream>>>(p, p);
    DiffSeg dr = dRuSeg(L[0]);
    k_diffM<0, -1><<<dr.nblk, 256, 0, stream>>>(dr, dr, Sh);
    G3RuSeg gr = ruSeg(L[0], P1);
    k_g3ru<<<gr.nblk, 512, 0, stream>>>(gr, gr);
    DiffSeg dc = dCdSeg(L[0]);
    k_diffM<2, -1><<<dc.nblk, 256, 0, stream>>>(dc, dc, Sh);
    G3CdSeg gc = cdSeg(L[0], P1, P0, nullptr, nullptr, 0);
    tgtA(gc, L[0], 0);          // l0 state <- P(0)
    tgtB(gc, L[1], 64);         // l1 inp   <- P(0)
    tgtX(gc, xin + (size_t)1 * NB * 2);
    k_g3cd<<<gc.nblk, 256, 0, stream>>>(gc, gc);
  }
  // ---- encoder steady: l0(t) ∥ l1(t-1), prep fused ----
  for (int t = 1; t < TT; t++) {
    const float* Pold = P[(t - 1) & 1];
    float* Pnew = P[t & 1];
    DiffSeg dr0 = dRuSeg(L[0]), dr1 = dRuSeg(L[1]);
    k_diffM<0, 1><<<dr0.nblk + dr1.nblk, 256, 0, stream>>>(dr0, dr1, Sh);
    G3RuSeg gr0 = ruSeg(L[0], Pold), gr1 = ruSeg(L[1], st1);
    k_g3ru<<<gr0.nblk + gr1.nblk, 512, 0, stream>>>(gr0, gr1);
    DiffSeg dc0 = dCdSeg(L[0]), dc1 = dCdSeg(L[1]);
    k_diffM<2, 3><<<dc0.nblk + dc1.nblk, 256, 0, stream>>>(dc0, dc1, Sh);
    G3CdSeg gc0 = cdSeg(L[0], Pold, Pnew, nullptr, nullptr, 0);
    tgtA(gc0, L[0], 0);         // l0 state <- P(t)
    tgtB(gc0, L[1], 64);        // l1 inp   <- P(t)
    G3CdSeg gc1 = cdSeg(L[1], st1, st1, nullptr, nullptr, 0);
    tgtA(gc1, L[1], 0);         // l1 state <- st1(t-1)
    if (t < TT - 1) tgtX(gc1, xin + (size_t)(t + 1) * NB * 2);
    k_g3cd<<<gc0.nblk + gc1.nblk, 256, 0, stream>>>(gc0, gc1);
  }
  // ---- encoder final: l1 timestep 11 (inputs already in place) ----
  {
    DiffSeg dr = dRuSeg(L[1]);
    k_diffM<1, -1><<<dr.nblk, 256, 0, stream>>>(dr, dr, Sh);
    G3RuSeg gr = ruSeg(L[1], st1);
    k_g3ru<<<gr.nblk, 512, 0, stream>>>(gr, gr);
    DiffSeg dc = dCdSeg(L[1]);
    k_diffM<3, -1><<<dc.nblk, 256, 0, stream>>>(dc, dc, Sh);
    G3CdSeg gc = cdSeg(L[1], st1, st1, nullptr, nullptr, 0);
    k_g3cd<<<gc.nblk, 256, 0, stream>>>(gc, gc);
  }

  // ---- decoder: sequential, prep fused into g3cd epilogues (as R14) ----
  {
    PrepSeg pd0 = prepSeg(L[2], decin, P1);
    PrepSeg pd1 = prepSeg(L[3], P1, st1);
    k_prepM<<<pd0.nblk + pd1.nblk, 256, 0, stream>>>(pd0, pd1);
  }
  for (int t = 0; t < TT; t++) {
    DiffSeg dr0 = dRuSeg(L[2]);
    k_diffM<0, -1><<<dr0.nblk, 256, 0, stream>>>(dr0, dr0, Sh);
    G3RuSeg gr0 = ruSeg(L[2], P1);
    k_g3ru<<<gr0.nblk, 512, 0, stream>>>(gr0, gr0);
    DiffSeg dc0 = dCdSeg(L[2]);
    k_diffM<2, -1><<<dc0.nblk, 256, 0, stream>>>(dc0, dc0, Sh);
    G3CdSeg g0 = cdSeg(L[2], P1, P1, nullptr, nullptr, 0);
    tgtA(g0, L[2], 0);          // l0 state
    tgtB(g0, L[3], 64);         // l1 inp
    k_g3cd<<<g0.nblk, 256, 0, stream>>>(g0, g0);
    DiffSeg dr1 = dRuSeg(L[3]);
    k_diffM<1, -1><<<dr1.nblk, 256, 0, stream>>>(dr1, dr1, Sh);
    G3RuSeg gr1 = ruSeg(L[3], st1);
    k_g3ru<<<gr1.nblk, 512, 0, stream>>>(gr1, gr1);
    DiffSeg dc1 = dCdSeg(L[3]);
    k_diffM<3, -1><<<dc1.nblk, 256, 0, stream>>>(dc1, dc1, Sh);
    G3CdSeg g1 = cdSeg(L[3], st1, st1, outW, outB, t);
    tgtA(g1, L[3], 0);          // l1 state
    g1.yPh = L[2].YcRh; g1.yPl = L[2].YcRl; g1.hPh = L[2].hh; g1.hPl = L[2].hl;
    g1.cwP = 72; g1.baseP = 64; g1.strP = 448;
    k_g3cd<<<g1.nblk, 256, 0, stream>>>(g1, g1);
  }
}

// Round 16
// 4955.258 us; speedup vs baseline: 1.5227x; 1.3397x over previous
//
#include <hip/hip_runtime.h>
#include <math.h>

// DCRNN on MI355X — round 16: R15 + coalesced g3ru/g3cd epilogues.
// Block row remap: fixed b (bloc), 64 consecutive n (ngrp) -> Yc c-major
// writes become 128B runs; gate outputs staged in LDS float tile, packed
// uint2 write phases. Values bit-identical: absmax must stay 6.103516e-05.

#define NN 1024
#define BB 16
#define TT 12
#define HH 64
#define NB (NN*BB)      // 16384

typedef unsigned short u16;
typedef unsigned int u32;
typedef __attribute__((ext_vector_type(8))) short sv8;
typedef __attribute__((ext_vector_type(4))) float f32x4;
typedef __attribute__((ext_vector_type(16))) float f32x16;

__device__ __forceinline__ void gload16(const void* g, void* l) {
  __builtin_amdgcn_global_load_lds(
      (const __attribute__((address_space(1))) void*)(unsigned long long)(g),
      (__attribute__((address_space(3))) void*)(l), 16, 0, 0);
}

#define WAIT_BAR(N) asm volatile("s_waitcnt vmcnt(" #N ")\n\ts_barrier" ::: "memory")
#define BAR() asm volatile("s_barrier" ::: "memory")

template<int NX, int NY, int NZ>
__device__ __forceinline__ void xcdmap(int bid, int& x, int& y, int& z) {
  constexpr int ZREP = 8 / NZ;
  constexpr int YH = NY / ZREP;
  int chunk = bid & 7, pos = bid >> 3;
  z = chunk / ZREP;
  int yh = chunk % ZREP;
  x = pos % NX;
  y = yh * YH + pos / NX;
}

__device__ __forceinline__ int swz(int row, int g) {
  int rp = row >> 1;
  int j = ((row & 1) << 2) | g;
  return (rp << 3) | (j ^ (rp & 7));
}

__device__ __forceinline__ u16 bf16_rne(float x) {
  u32 u = __float_as_uint(x);
  return (u16)((u + 0x7FFFu + ((u >> 16) & 1u)) >> 16);
}
__device__ __forceinline__ void split2(float x, u16& h, u16& l) {
  h = bf16_rne(x);
  float hf = __uint_as_float(((u32)h) << 16);
  l = bf16_rne(x - hf);
}

__global__ __launch_bounds__(256) void k_zero(float* p, int n) {
  int i = blockIdx.x * 256 + threadIdx.x;
  if (i < n) p[i] = 0.f;
}

// zero l1 state cols of Yc1 and h1 (hi+lo) — initial st1 = 0 for encoder t=1
__global__ __launch_bounds__(256) void k_init1(u16* __restrict__ ych, u16* __restrict__ ycl,
                                               u16* __restrict__ hh, u16* __restrict__ hl) {
  int idx = blockIdx.x * 256 + threadIdx.x;
  if (idx >= 16 * 64 * NN) return;
  int n = idx & (NN - 1);
  int t = idx >> 10;
  int b = t >> 6, d = t & 63;
  ych[(size_t)(b * 128 + d) * NN + n] = 0;
  ycl[(size_t)(b * 128 + d) * NN + n] = 0;
  int nb = (n << 4) + b;
  hh[(size_t)nb * 704 + d] = 0;
  hl[(size_t)nb * 704 + d] = 0;
}

__global__ __launch_bounds__(256) void k_transpose_in(const float* __restrict__ in,
                                                      float* __restrict__ xt) {
  int idx = blockIdx.x * 256 + threadIdx.x;
  if (idx >= BB * TT * NN * 2) return;
  int i = idx & 1;
  int n = (idx >> 1) & (NN - 1);
  int bt = idx >> 11;
  int t = bt % TT, b = bt / TT;
  xt[(size_t)t * (NB * 2) + (size_t)(n * BB + b) * 2 + i] = in[idx];
}

__global__ __launch_bounds__(256) void k_splitS(const float* __restrict__ s,
                                                u16* __restrict__ sh, u16* __restrict__ sl) {
  int idx = blockIdx.x * 256 + threadIdx.x;
  if (idx >= 2 * NN * NN) return;
  u16 h, l; split2(s[idx], h, l);
  sh[idx] = h; sl[idx] = l;
}

__global__ __launch_bounds__(256) void k_transpS(const u16* __restrict__ sh,
        const u16* __restrict__ sl, u16* __restrict__ sth, u16* __restrict__ stl) {
  int idx = blockIdx.x * 256 + threadIdx.x;
  if (idx >= 2 * NN * NN) return;
  int j = idx & (NN - 1);
  int k = (idx >> 10) & (NN - 1);
  int z = idx >> 20;
  size_t src = ((size_t)z << 20) | ((size_t)j << 10) | (size_t)k;
  sth[idx] = sh[src];
  stl[idx] = sl[src];
}

__global__ __launch_bounds__(256) void k_padWt(const float* __restrict__ W,
        u16* __restrict__ Wth, u16* __restrict__ Wtl,
        int indim, int Dp, int KTa, int dout) {
  int idx = blockIdx.x * 256 + threadIdx.x;
  if (idx >= dout * KTa) return;
  int kk = idx % KTa, o = idx / KTa;
  int blk = kk / Dp, d = kk - blk * Dp;
  int Dreal = indim + 64;
  float v = 0.f;
  if (blk < 5) {
    int dorig = -1;
    if (d < 64) dorig = indim + d;
    else if (d - 64 < indim) dorig = d - 64;
    if (dorig >= 0) v = W[(size_t)(blk * Dreal + dorig) * dout + o];
  }
  u16 h, l; split2(v, h, l);
  Wth[idx] = h; Wtl[idx] = l;
}

__global__ __launch_bounds__(256) void k_padWtCand(const float* __restrict__ W,
        u16* __restrict__ Wth, u16* __restrict__ Wtl,
        int indim, int Dp, int KTa, int dout) {
  int idx = blockIdx.x * 256 + threadIdx.x;
  if (idx >= dout * KTa) return;
  int kk = idx % KTa, o = idx / KTa;
  int c = 64 + kk;
  int Dreal = indim + 64;
  float v = 0.f;
  if (c >= KTa) {
    int d = c - KTa;
    v = W[(size_t)(indim + d) * dout + o];
  } else {
    int blk = c / Dp, d = c - blk * Dp;
    if (blk == 0) {
      int di = d - 64;
      if (di < indim) v = W[(size_t)di * dout + o];
    } else {
      if (d < 64) v = W[(size_t)(blk * Dreal + indim + d) * dout + o];
      else if (d - 64 < indim) v = W[(size_t)(blk * Dreal + (d - 64)) * dout + o];
    }
  }
  u16 h, l; split2(v, h, l);
  Wth[idx] = h; Wtl[idx] = l;
}

struct PrepSeg {
  const float *inp, *st;
  u16 *ych, *ycl, *hh, *hl;
  int indim, CW, STR, nblk;
};
__global__ __launch_bounds__(256) void k_prepM(PrepSeg s0, PrepSeg s1) {
  const bool first = (int)blockIdx.x < s0.nblk;
  const PrepSeg s = first ? s0 : s1;
  const int c = first ? blockIdx.x : blockIdx.x - s0.nblk;
  int n0 = threadIdx.x << 2;
  int b = c / s.CW, d = c - b * s.CW;
  u16 h4[4], l4[4];
  #pragma unroll
  for (int r = 0; r < 4; r++) {
    int nb = ((n0 + r) << 4) + b;
    float v = 0.f;
    if (d < 64) v = s.st[(size_t)nb * HH + d];
    else if (d - 64 < s.indim) v = s.inp[(size_t)nb * s.indim + (d - 64)];
    split2(v, h4[r], l4[r]);
    s.hh[(size_t)nb * s.STR + d] = h4[r];
    s.hl[(size_t)nb * s.STR + d] = l4[r];
  }
  uint2 ph, pl;
  ph.x = (u32)h4[0] | ((u32)h4[1] << 16); ph.y = (u32)h4[2] | ((u32)h4[3] << 16);
  pl.x = (u32)l4[0] | ((u32)l4[1] << 16); pl.y = (u32)l4[2] | ((u32)l4[3] << 16);
  *(uint2*)&s.ych[(size_t)c * NN + n0] = ph;
  *(uint2*)&s.ycl[(size_t)c * NN + n0] = pl;
}

struct StageMap {
  int row1, g1, row2, g2;
  __device__ StageMap(int tid) {
    int rp = tid >> 3, jx = (tid & 7) ^ (rp & 7);
    row1 = (rp << 1) | (jx >> 2); g1 = jx & 3;
    int s = tid + 256; rp = s >> 3; jx = (s & 7) ^ (rp & 7);
    row2 = (rp << 1) | (jx >> 2); g2 = jx & 3;
  }
};

// ---------- S^2 (setup, runs once; full 3-term precision) ----------
__global__ __launch_bounds__(256) void k_sq(
    const u16* __restrict__ Sh, const u16* __restrict__ Sl,
    const u16* __restrict__ STh, const u16* __restrict__ STl,
    u16* __restrict__ Oh, u16* __restrict__ Ol)
{
  __shared__ __attribute__((aligned(16))) u16 lA[2][2][4096];
  __shared__ __attribute__((aligned(16))) u16 lB[2][2][4096];
  const int tid = threadIdx.x;
  const int lane = tid & 63, wave = tid >> 6;
  int bx, by, z;
  xcdmap<8, 8, 2>(blockIdx.x, bx, by, z);
  const int a0 = bx << 7, b0 = by << 7;
  const int wc0 = (wave & 1) << 6, wn0 = (wave >> 1) << 6;
  StageMap sm(tid);
  const u16* pa1h = Sh + (size_t)z * NN * NN + (size_t)(a0 + sm.row1) * NN + sm.g1 * 8;
  const u16* pa2h = Sh + (size_t)z * NN * NN + (size_t)(a0 + sm.row2) * NN + sm.g2 * 8;
  const u16* pa1l = Sl + (size_t)z * NN * NN + (size_t)(a0 + sm.row1) * NN + sm.g1 * 8;
  const u16* pa2l = Sl + (size_t)z * NN * NN + (size_t)(a0 + sm.row2) * NN + sm.g2 * 8;
  const u16* pb1h = STh + (size_t)z * NN * NN + (size_t)(b0 + sm.row1) * NN + sm.g1 * 8;
  const u16* pb2h = STh + (size_t)z * NN * NN + (size_t)(b0 + sm.row2) * NN + sm.g2 * 8;
  const u16* pb1l = STl + (size_t)z * NN * NN + (size_t)(b0 + sm.row1) * NN + sm.g1 * 8;
  const u16* pb2l = STl + (size_t)z * NN * NN + (size_t)(b0 + sm.row2) * NN + sm.g2 * 8;

  f32x16 acc[2][2];
  #pragma unroll
  for (int i = 0; i < 2; i++)
    #pragma unroll
    for (int j = 0; j < 2; j++)
      #pragma unroll
      for (int e = 0; e < 16; e++) acc[i][j][e] = 0.f;

  auto stage = [&](int buf, int k0) {
    gload16(pa1h + k0, &lA[buf][0][tid * 8]);
    gload16(pa2h + k0, &lA[buf][0][tid * 8 + 2048]);
    gload16(pa1l + k0, &lA[buf][1][tid * 8]);
    gload16(pa2l + k0, &lA[buf][1][tid * 8 + 2048]);
    gload16(pb1h + k0, &lB[buf][0][tid * 8]);
    gload16(pb2h + k0, &lB[buf][0][tid * 8 + 2048]);
    gload16(pb1l + k0, &lB[buf][1][tid * 8]);
    gload16(pb2l + k0, &lB[buf][1][tid * 8 + 2048]);
  };
  stage(0, 0);
  __syncthreads();
  int cur = 0;
  for (int kt = 0; kt < 32; kt++) {
    if (kt < 31) stage(cur ^ 1, (kt + 1) * 32);
    #pragma unroll
    for (int kh = 0; kh < 2; kh++) {
      sv8 vah[2], vaL[2], vbh[2], vbL[2];
      int gsel = (kh << 1) | (lane >> 5);
      #pragma unroll
      for (int f = 0; f < 2; f++) {
        int offa = swz(wc0 + f * 32 + (lane & 31), gsel) * 8;
        vah[f] = *(const sv8*)&lA[cur][0][offa];
        vaL[f] = *(const sv8*)&lA[cur][1][offa];
        int offb = swz(wn0 + f * 32 + (lane & 31), gsel) * 8;
        vbh[f] = *(const sv8*)&lB[cur][0][offb];
        vbL[f] = *(const sv8*)&lB[cur][1][offb];
      }
      #pragma unroll
      for (int fm = 0; fm < 2; fm++)
        #pragma unroll
        for (int fn = 0; fn < 2; fn++) {
          acc[fm][fn] = __builtin_amdgcn_mfma_f32_32x32x16_bf16(vah[fm], vbh[fn], acc[fm][fn], 0, 0, 0);
          acc[fm][fn] = __builtin_amdgcn_mfma_f32_32x32x16_bf16(vah[fm], vbL[fn], acc[fm][fn], 0, 0, 0);
          acc[fm][fn] = __builtin_amdgcn_mfma_f32_32x32x16_bf16(vaL[fm], vbh[fn], acc[fm][fn], 0, 0, 0);
        }
    }
    __syncthreads();
    cur ^= 1;
  }
  u16* oh = Oh + (size_t)z * NN * NN;
  u16* ol = Ol + (size_t)z * NN * NN;
  #pragma unroll
  for (int fm = 0; fm < 2; fm++)
    #pragma unroll
    for (int q = 0; q < 4; q++) {
      int m4 = a0 + wc0 + fm * 32 + q * 8 + ((lane >> 5) << 2);
      #pragma unroll
      for (int fn = 0; fn < 2; fn++) {
        int kc = b0 + wn0 + fn * 32 + (lane & 31);
        #pragma unroll
        for (int r = 0; r < 4; r++) {
          u16 hi, lo; split2(acc[fm][fn][q * 4 + r], hi, lo);
          oh[(size_t)(m4 + r) * NN + kc] = hi;
          ol[(size_t)(m4 + r) * NN + kc] = lo;
        }
      }
    }
}

// ---------- diffusion (BK=32, counted vmcnt, 2-term, coalesced epilogue) ----------
struct DiffSeg { const u16 *Ah, *Al; u16 *hh, *hl; int nblk; };

constexpr int bn_of(int V) { return (V == 1) ? 128 : 64; }

template<int V>
__device__ __forceinline__ void diffuse_body(int bid, const DiffSeg s,
    const u16* __restrict__ Sh, u16* lds)
{
  constexpr int BN  = bn_of(V);
  constexpr int DP  = (V == 0 || V == 2) ? 72 : 128;
  constexpr int KTA = (V == 0 || V == 2) ? 384 : 640;
  constexpr int STR = KTA + 64;
  constexpr int CW  = (V == 0) ? 72 : ((V == 1) ? 128 : 64);
  constexpr int NX  = (V == 0) ? 9 : ((V == 1) ? 16 : 8);
  constexpr int NY  = (BN == 128) ? 8 : 16;
  constexpr int FN  = BN / 64;

  u16* sA = lds;
  u16* sB = lds + 4 * 4096;
  const int tid = threadIdx.x;
  const int lane = tid & 63, wave = tid >> 6;
  int bx, by, z;
  xcdmap<NX, NY, 4>(bid, bx, by, z);
  const int a0 = bx << 7;
  const int b0 = by * BN;
  const int wc0 = (wave & 1) << 6;
  const int wn0 = (wave >> 1) * (BN / 2);
  StageMap sm(tid);
  const u16* pa1h = s.Ah + (size_t)(a0 + sm.row1) * NN + sm.g1 * 8;
  const u16* pa2h = s.Ah + (size_t)(a0 + sm.row2) * NN + sm.g2 * 8;
  const u16* pa1l = s.Al + (size_t)(a0 + sm.row1) * NN + sm.g1 * 8;
  const u16* pa2l = s.Al + (size_t)(a0 + sm.row2) * NN + sm.g2 * 8;
  const u16* pb1h = Sh + (size_t)z * NN * NN + (size_t)(b0 + sm.row1) * NN + sm.g1 * 8;
  const u16* pb2h = Sh + (size_t)z * NN * NN + (size_t)(b0 + sm.row2) * NN + sm.g2 * 8;

  f32x16 acc[2][FN];
  #pragma unroll
  for (int i = 0; i < 2; i++)
    #pragma unroll
    for (int j = 0; j < FN; j++)
      #pragma unroll
      for (int e = 0; e < 16; e++) acc[i][j][e] = 0.f;

  auto stage = [&](int buf, int k0) {
    gload16(pa1h + k0, sA + (buf * 2 + 0) * 4096 + tid * 8);
    gload16(pa1l + k0, sA + (buf * 2 + 1) * 4096 + tid * 8);
    gload16(pa2h + k0, sA + (buf * 2 + 0) * 4096 + tid * 8 + 2048);
    gload16(pa2l + k0, sA + (buf * 2 + 1) * 4096 + tid * 8 + 2048);
    gload16(pb1h + k0, sB + buf * (BN * 32) + tid * 8);
    if constexpr (BN == 128)
      gload16(pb2h + k0, sB + buf * (BN * 32) + tid * 8 + 2048);
  };
  stage(0, 0);
  int cur = 0;
  for (int kt = 0; kt < 32; kt++) {
    if (kt < 31) {
      stage(cur ^ 1, (kt + 1) * 32);
      if constexpr (BN == 128) { WAIT_BAR(6); } else { WAIT_BAR(5); }
    } else {
      WAIT_BAR(0);
    }
    #pragma unroll
    for (int kh = 0; kh < 2; kh++) {
      sv8 vah[2], vaL[2], vbh[FN];
      int gsel = (kh << 1) | (lane >> 5);
      #pragma unroll
      for (int f = 0; f < 2; f++) {
        int offa = swz(wc0 + f * 32 + (lane & 31), gsel) * 8;
        vah[f] = *(const sv8*)(sA + (cur * 2 + 0) * 4096 + offa);
        vaL[f] = *(const sv8*)(sA + (cur * 2 + 1) * 4096 + offa);
      }
      #pragma unroll
      for (int f = 0; f < FN; f++) {
        int offb = swz(wn0 + f * 32 + (lane & 31), gsel) * 8;
        vbh[f] = *(const sv8*)(sB + cur * (BN * 32) + offb);
      }
      #pragma unroll
      for (int fm = 0; fm < 2; fm++)
        #pragma unroll
        for (int fn = 0; fn < FN; fn++) {
          acc[fm][fn] = __builtin_amdgcn_mfma_f32_32x32x16_bf16(vah[fm], vbh[fn], acc[fm][fn], 0, 0, 0);
          acc[fm][fn] = __builtin_amdgcn_mfma_f32_32x32x16_bf16(vaL[fm], vbh[fn], acc[fm][fn], 0, 0, 0);
        }
    }
    BAR();
    cur ^= 1;
  }

  // ---- coalesced epilogue: LDS transpose [m][132], two passes (hi, lo) ----
  const int blkoff = (1 + ((z & 1) << 1) + (z >> 1)) * DP;
  u16* const dsts[2] = {s.hh, s.hl};
  #pragma unroll
  for (int p = 0; p < 2; p++) {
    #pragma unroll
    for (int fm = 0; fm < 2; fm++)
      #pragma unroll
      for (int q = 0; q < 4; q++) {
        int cl = wc0 + fm * 32 + q * 8 + ((lane >> 5) << 2);
        #pragma unroll
        for (int fn = 0; fn < FN; fn++) {
          int ml = wn0 + fn * 32 + (lane & 31);
          u16 v4[4];
          #pragma unroll
          for (int r = 0; r < 4; r++) {
            u16 hi, lo; split2(acc[fm][fn][q * 4 + r], hi, lo);
            v4[r] = p ? lo : hi;
          }
          uint2 pk;
          pk.x = (u32)v4[0] | ((u32)v4[1] << 16);
          pk.y = (u32)v4[2] | ((u32)v4[3] << 16);
          *(uint2*)&lds[ml * 132 + cl] = pk;
        }
      }
    __syncthreads();
    u16* dst = dsts[p];
    #pragma unroll
    for (int i = 0; i < BN * 32 / 256; i++) {
      int w = tid + (i << 8);
      int ml = w >> 5, c4 = (w & 31) << 2;
      uint2 pk = *(uint2*)&lds[ml * 132 + c4];
      int cg = a0 + c4;
      int bq = cg / CW, dq = cg - bq * CW;
      int nb = ((b0 + ml) << 4) + bq;
      *(uint2*)&dst[(size_t)nb * STR + blkoff + dq] = pk;
    }
    __syncthreads();
  }
}

template<int VA, int VB>
__global__ __launch_bounds__(256) void k_diffM(DiffSeg s0, DiffSeg s1,
    const u16* __restrict__ Sh) {
  constexpr int BNA = bn_of(VA);
  constexpr int BNB = (VB >= 0) ? bn_of(VB) : 64;
  constexpr int MB = BNA > BNB ? BNA : BNB;
  constexpr int STG = 4 * 4096 + 2 * MB * 32;
  constexpr int TRN = MB * 132;
  constexpr int TOT = STG > TRN ? STG : TRN;
  __shared__ __attribute__((aligned(16))) u16 lds[TOT];
  if ((int)blockIdx.x < s0.nblk) {
    diffuse_body<VA>(blockIdx.x, s0, Sh, lds);
  } else {
    if constexpr (VB >= 0)
      diffuse_body<VB>(blockIdx.x - s0.nblk, s1, Sh, lds);
  }
}

// ---------- gemm-ru (dbuf, NL=3) + fused cand-prep, coalesced epilogue ----------
// block rows: fixed b (bloc = bid&15), n = ngrp*64 + rloc (ngrp = bid>>4)
struct G3RuSeg {
  const u16 *Ah, *Al, *Bh, *Bl;
  const float *bias, *stold;
  float *ru;
  u16 *ych, *ycl, *hh, *hl;
  int KTa, STR, nblk;
};
__global__ __launch_bounds__(512) void k_g3ru(G3RuSeg s0, G3RuSeg s1) {
  __shared__ __attribute__((aligned(16))) u16 lAh[2][2048];
  __shared__ __attribute__((aligned(16))) u16 lAl[2][2048];
  __shared__ __attribute__((aligned(16))) u16 lBh[2][4096];
  __shared__ __attribute__((aligned(16))) u16 lBl[2][4096];
  __shared__ float pstF[64][65];
  const bool first = (int)blockIdx.x < s0.nblk;
  const G3RuSeg s = first ? s0 : s1;
  const int bid = first ? blockIdx.x : blockIdx.x - s0.nblk;
  const int tid = threadIdx.x;
  const int lane = tid & 63, wave = tid >> 6;
  const int bloc = bid & 15, ngrp = bid >> 4;
  const int n0g = ngrp * 64;
  const int wr0 = (wave & 1) << 5;
  const int wn0 = (wave >> 1) << 5;
  const int gw = lane >> 4, rsel = lane & 15;
  const int sAi = tid & 255;
  int rp = sAi >> 3, jx = (sAi & 7) ^ (rp & 7);
  const int rowA = (rp << 1) | (jx >> 2), gAc = jx & 3;
  rp = tid >> 3; jx = (tid & 7) ^ (rp & 7);
  const int rowB = (rp << 1) | (jx >> 2), gBc = jx & 3;
  const size_t nbA = (size_t)(((n0g + rowA) << 4) + bloc);

  f32x4 acc[2][2];
  #pragma unroll
  for (int i = 0; i < 2; i++)
    #pragma unroll
    for (int j = 0; j < 2; j++) acc[i][j] = (f32x4){0.f, 0.f, 0.f, 0.f};

  auto stg = [&](int buf, int k0) {
    if (tid < 256) gload16(s.Ah + nbA * s.STR + k0 + gAc * 8, &lAh[buf][sAi * 8]);
    else           gload16(s.Al + nbA * s.STR + k0 + gAc * 8, &lAl[buf][sAi * 8]);
    gload16(s.Bh + (size_t)rowB * s.KTa + k0 + gBc * 8, &lBh[buf][tid * 8]);
    gload16(s.Bl + (size_t)rowB * s.KTa + k0 + gBc * 8, &lBl[buf][tid * 8]);
  };
  const int NI = s.KTa >> 5;
  stg(0, 0);
  int cur = 0;
  for (int i = 0; i < NI; i++) {
    if (i < NI - 1) {
      stg(cur ^ 1, (i + 1) * 32);
      WAIT_BAR(3);
    } else {
      WAIT_BAR(0);
    }
    sv8 vah[2], vaL[2], vbh[2], vbL[2];
    #pragma unroll
    for (int f = 0; f < 2; f++) {
      int offa = swz(wr0 + f * 16 + rsel, gw) * 8;
      vah[f] = *(const sv8*)&lAh[cur][offa];
      vaL[f] = *(const sv8*)&lAl[cur][offa];
      int offb = swz(wn0 + f * 16 + rsel, gw) * 8;
      vbh[f] = *(const sv8*)&lBh[cur][offb];
      vbL[f] = *(const sv8*)&lBl[cur][offb];
    }
    #pragma unroll
    for (int fm = 0; fm < 2; fm++)
      #pragma unroll
      for (int fn = 0; fn < 2; fn++) {
        acc[fm][fn] = __builtin_amdgcn_mfma_f32_16x16x32_bf16(vah[fm], vbh[fn], acc[fm][fn], 0, 0, 0);
        acc[fm][fn] = __builtin_amdgcn_mfma_f32_16x16x32_bf16(vah[fm], vbL[fn], acc[fm][fn], 0, 0, 0);
        acc[fm][fn] = __builtin_amdgcn_mfma_f32_16x16x32_bf16(vaL[fm], vbh[fn], acc[fm][fn], 0, 0, 0);
      }
    BAR();
    cur ^= 1;
  }

  // phase 1: sigmoid, ru write (row-contig), rv -> pstF
  #pragma unroll
  for (int fm = 0; fm < 2; fm++) {
    #pragma unroll
    for (int r = 0; r < 4; r++) {
      int rloc = wr0 + fm * 16 + ((lane >> 4) << 2) + r;
      size_t nb = (size_t)(((n0g + rloc) << 4) + bloc);
      #pragma unroll
      for (int fn = 0; fn < 2; fn++) {
        int o = wn0 + fn * 16 + rsel;
        float v = acc[fm][fn][r] + s.bias[o];
        float sig = 1.f / (1.f + expf(-v));
        s.ru[nb * 128 + o] = sig;
        if (o < 64) pstF[rloc][o] = sig * s.stold[nb * HH + o];
      }
    }
  }
  __syncthreads();
  // phase 2: coalesced yc (c-major: c = bloc*64+o over 64 consecutive n)
  #pragma unroll
  for (int i = 0; i < 2; i++) {
    int slot = tid + (i << 9);
    int o = slot >> 4, nq = (slot & 15) << 2;
    u16 hi4[4], lo4[4];
    #pragma unroll
    for (int j = 0; j < 4; j++) split2(pstF[nq + j][o], hi4[j], lo4[j]);
    uint2 ph, pl;
    ph.x = (u32)hi4[0] | ((u32)hi4[1] << 16); ph.y = (u32)hi4[2] | ((u32)hi4[3] << 16);
    pl.x = (u32)lo4[0] | ((u32)lo4[1] << 16); pl.y = (u32)lo4[2] | ((u32)lo4[3] << 16);
    size_t yoff = (size_t)(bloc * 64 + o) * NN + n0g + nq;
    *(uint2*)&s.ych[yoff] = ph;
    *(uint2*)&s.ycl[yoff] = pl;
  }
  // phase 3: coalesced h rows (128B run per row)
  #pragma unroll
  for (int i = 0; i < 2; i++) {
    int slot = tid + (i << 9);
    int rloc = slot >> 4, oq = (slot & 15) << 2;
    size_t nb = (size_t)(((n0g + rloc) << 4) + bloc);
    u16 hi4[4], lo4[4];
    #pragma unroll
    for (int j = 0; j < 4; j++) split2(pstF[rloc][oq + j], hi4[j], lo4[j]);
    uint2 ph, pl;
    ph.x = (u32)hi4[0] | ((u32)hi4[1] << 16); ph.y = (u32)hi4[2] | ((u32)hi4[3] << 16);
    pl.x = (u32)lo4[0] | ((u32)lo4[1] << 16); pl.y = (u32)lo4[2] | ((u32)lo4[3] << 16);
    *(uint2*)&s.hh[nb * s.STR + s.KTa + oq] = ph;
    *(uint2*)&s.hl[nb * s.STR + s.KTa + oq] = pl;
  }
}

// ---------- gemm-cand (dbuf, NL=4) + fused prep/proj, coalesced epilogue ----------
struct G3CdSeg {
  const u16 *Ah, *Al, *Bh, *Bl;
  const float *bias, *ru, *stold;
  float *stout;
  u16 *yAh, *yAl, *hAh, *hAl; int cwA, baseA, strA;
  u16 *yBh, *yBl, *hBh, *hBl; int cwB, baseB, strB;
  const float *ow, *ob;
  float *outg, *decin;
  u16 *yPh, *yPl, *hPh, *hPl; int cwP, baseP, strP;
  const float *xp;
  u16 *yXh, *yXl, *hXh, *hXl;
  int t, KTa, STR, nblk;
};
__global__ __launch_bounds__(256) void k_g3cd(G3CdSeg s0, G3CdSeg s1) {
  __shared__ __attribute__((aligned(16))) u16 lAh[2][2048];
  __shared__ __attribute__((aligned(16))) u16 lAl[2][2048];
  __shared__ __attribute__((aligned(16))) u16 lBh[2][2048];
  __shared__ __attribute__((aligned(16))) u16 lBl[2][2048];
  __shared__ float pst[64][65];
  const bool first = (int)blockIdx.x < s0.nblk;
  const G3CdSeg s = first ? s0 : s1;
  const int bid = first ? blockIdx.x : blockIdx.x - s0.nblk;
  const int tid = threadIdx.x;
  const int lane = tid & 63, wave = tid >> 6;
  const int bloc = bid & 15, ngrp = bid >> 4;
  const int n0g = ngrp * 64;
  const int wr0 = (wave & 1) << 5;
  const int wn0 = (wave >> 1) << 5;
  const int gw = lane >> 4, rsel = lane & 15;
  int rp = tid >> 3, jx = (tid & 7) ^ (rp & 7);
  const int rowA = (rp << 1) | (jx >> 2), gAc = jx & 3;
  const size_t nbA = (size_t)(((n0g + rowA) << 4) + bloc);

  f32x4 acc[2][2];
  #pragma unroll
  for (int i = 0; i < 2; i++)
    #pragma unroll
    for (int j = 0; j < 2; j++) acc[i][j] = (f32x4){0.f, 0.f, 0.f, 0.f};

  auto stg = [&](int buf, int k0) {
    gload16(s.Ah + nbA * s.STR + 64 + k0 + gAc * 8, &lAh[buf][tid * 8]);
    gload16(s.Al + nbA * s.STR + 64 + k0 + gAc * 8, &lAl[buf][tid * 8]);
    gload16(s.Bh + (size_t)rowA * s.KTa + k0 + gAc * 8, &lBh[buf][tid * 8]);
    gload16(s.Bl + (size_t)rowA * s.KTa + k0 + gAc * 8, &lBl[buf][tid * 8]);
  };
  const int NI = s.KTa >> 5;
  stg(0, 0);
  int cur = 0;
  for (int i = 0; i < NI; i++) {
    if (i < NI - 1) {
      stg(cur ^ 1, (i + 1) * 32);
      WAIT_BAR(4);
    } else {
      WAIT_BAR(0);
    }
    sv8 vah[2], vaL[2], vbh[2], vbL[2];
    #pragma unroll
    for (int f = 0; f < 2; f++) {
      int offa = swz(wr0 + f * 16 + rsel, gw) * 8;
      vah[f] = *(const sv8*)&lAh[cur][offa];
      vaL[f] = *(const sv8*)&lAl[cur][offa];
      int offb = swz(wn0 + f * 16 + rsel, gw) * 8;
      vbh[f] = *(const sv8*)&lBh[cur][offb];
      vbL[f] = *(const sv8*)&lBl[cur][offb];
    }
    #pragma unroll
    for (int fm = 0; fm < 2; fm++)
      #pragma unroll
      for (int fn = 0; fn < 2; fn++) {
        acc[fm][fn] = __builtin_amdgcn_mfma_f32_16x16x32_bf16(vah[fm], vbh[fn], acc[fm][fn], 0, 0, 0);
        acc[fm][fn] = __builtin_amdgcn_mfma_f32_16x16x32_bf16(vah[fm], vbL[fn], acc[fm][fn], 0, 0, 0);
        acc[fm][fn] = __builtin_amdgcn_mfma_f32_16x16x32_bf16(vaL[fm], vbh[fn], acc[fm][fn], 0, 0, 0);
      }
    BAR();
    cur ^= 1;
  }

  // phase 1: GRU update, stout write (row-contig), ns -> pst
  #pragma unroll
  for (int fm = 0; fm < 2; fm++) {
    #pragma unroll
    for (int r = 0; r < 4; r++) {
      int rloc = wr0 + fm * 16 + ((lane >> 4) << 2) + r;
      size_t nb = (size_t)(((n0g + rloc) << 4) + bloc);
      #pragma unroll
      for (int fn = 0; fn < 2; fn++) {
        int o = wn0 + fn * 16 + rsel;
        float v = acc[fm][fn][r] + s.bias[o];
        float u = s.ru[nb * 128 + 64 + o];
        float sold = s.stold[nb * HH + o];
        float ns = u * sold + (1.f - u) * tanhf(v);
        s.stout[nb * HH + o] = ns;
        pst[rloc][o] = ns;
      }
    }
  }
  __syncthreads();
  // phase 2: coalesced y+h writes per target (A, then B)
  for (int tg = 0; tg < 2; tg++) {
    u16 *yh, *yl, *hh2, *hl2; int cw, base, str;
    if (tg == 0) {
      if (!s.yAh) continue;
      yh = s.yAh; yl = s.yAl; hh2 = s.hAh; hl2 = s.hAl; cw = s.cwA; base = s.baseA; str = s.strA;
    } else {
      if (!s.yBh) continue;
      yh = s.yBh; yl = s.yBl; hh2 = s.hBh; hl2 = s.hBl; cw = s.cwB; base = s.baseB; str = s.strB;
    }
    #pragma unroll
    for (int i = 0; i < 4; i++) {
      int slot = tid + (i << 8);
      int o = slot >> 4, nq = (slot & 15) << 2;
      u16 hi4[4], lo4[4];
      #pragma unroll
      for (int j = 0; j < 4; j++) split2(pst[nq + j][o], hi4[j], lo4[j]);
      uint2 ph, pl;
      ph.x = (u32)hi4[0] | ((u32)hi4[1] << 16); ph.y = (u32)hi4[2] | ((u32)hi4[3] << 16);
      pl.x = (u32)lo4[0] | ((u32)lo4[1] << 16); pl.y = (u32)lo4[2] | ((u32)lo4[3] << 16);
      size_t yoff = (size_t)(bloc * cw + base + o) * NN + n0g + nq;
      *(uint2*)&yh[yoff] = ph;
      *(uint2*)&yl[yoff] = pl;
    }
    #pragma unroll
    for (int i = 0; i < 4; i++) {
      int slot = tid + (i << 8);
      int rloc = slot >> 4, oq = (slot & 15) << 2;
      size_t nb = (size_t)(((n0g + rloc) << 4) + bloc);
      u16 hi4[4], lo4[4];
      #pragma unroll
      for (int j = 0; j < 4; j++) split2(pst[rloc][oq + j], hi4[j], lo4[j]);
      uint2 ph, pl;
      ph.x = (u32)hi4[0] | ((u32)hi4[1] << 16); ph.y = (u32)hi4[2] | ((u32)hi4[3] << 16);
      pl.x = (u32)lo4[0] | ((u32)lo4[1] << 16); pl.y = (u32)lo4[2] | ((u32)lo4[3] << 16);
      *(uint2*)&hh2[nb * str + base + oq] = ph;
      *(uint2*)&hl2[nb * str + base + oq] = pl;
    }
  }
  if (s.xp) {
    if (tid < 128) {
      int rloc = tid >> 1, d = tid & 1;
      size_t nb = (size_t)(((n0g + rloc) << 4) + bloc);
      float v = s.xp[nb * 2 + d];
      u16 hi, lo; split2(v, hi, lo);
      int c = bloc * 72 + 64 + d;
      s.yXh[(size_t)c * NN + n0g + rloc] = hi;
      s.yXl[(size_t)c * NN + n0g + rloc] = lo;
      s.hXh[nb * 448 + 64 + d] = hi;
      s.hXl[nb * 448 + 64 + d] = lo;
    }
  }
  if (s.ow) {
    if (tid < 64) {
      size_t nb = (size_t)(((n0g + tid) << 4) + bloc);
      float a2 = s.ob[0];
      #pragma unroll
      for (int o = 0; o < HH; o++) a2 += pst[tid][o] * s.ow[o];
      int n = n0g + tid;
      s.outg[((size_t)bloc * TT + s.t) * NN + n] = a2;
      s.decin[nb] = a2;
      if (s.yPh) {
        u16 hi, lo; split2(a2, hi, lo);
        int c = bloc * s.cwP + s.baseP;
        s.yPh[(size_t)c * NN + n] = hi;
        s.yPl[(size_t)c * NN + n] = lo;
        s.hPh[nb * s.strP + s.baseP] = hi;
        s.hPl[nb * s.strP + s.baseP] = lo;
      }
    }
  }
}

// ---------------- host ----------------
struct LayerH {
  u16 *YcRh, *YcRl, *YcCh, *YcCl, *hh, *hl;
  float *ru;
  u16 *Wrh, *Wrl, *Wch, *Wcl;
  const float *br, *bc;
  int indim, CW, KTa, STR, nfull;
};

extern "C" void kernel_launch(void* const* d_in, const int* in_sizes, int n_in,
                              void* d_out, int out_size, void* d_ws, size_t ws_size,
                              hipStream_t stream) {
  const float* inputs   = (const float*)d_in[0];
  const float* supports = (const float*)d_in[1];
  const float* Wsrc[8] = {(const float*)d_in[2], (const float*)d_in[4],
                          (const float*)d_in[6], (const float*)d_in[8],
                          (const float*)d_in[10], (const float*)d_in[12],
                          (const float*)d_in[14], (const float*)d_in[16]};
  const float* bias[8] = {(const float*)d_in[3], (const float*)d_in[5],
                          (const float*)d_in[7], (const float*)d_in[9],
                          (const float*)d_in[11], (const float*)d_in[13],
                          (const float*)d_in[15], (const float*)d_in[17]};
  const float* outW = (const float*)d_in[18];
  const float* outB = (const float*)d_in[19];
  float* out = (float*)d_out;

  char* cur = (char*)d_ws;
  auto alloc = [&](size_t bytes) -> char* {
    char* p = cur; cur += (bytes + 255) & ~(size_t)255; return p;
  };
  u16* Sh    = (u16*)alloc((size_t)4 * NN * NN * 2);
  u16* Sl    = (u16*)alloc((size_t)4 * NN * NN * 2);
  u16* YcR0h = (u16*)alloc((size_t)1152 * NN * 2);
  u16* YcR0l = (u16*)alloc((size_t)1152 * NN * 2);
  u16* YcR1h = (u16*)alloc((size_t)2048 * NN * 2);
  u16* YcR1l = (u16*)alloc((size_t)2048 * NN * 2);
  u16* h0h   = (u16*)alloc((size_t)NB * 448 * 2);
  u16* h0l   = (u16*)alloc((size_t)NB * 448 * 2);
  u16* h1h   = (u16*)alloc((size_t)NB * 704 * 2);
  u16* h1l   = (u16*)alloc((size_t)NB * 704 * 2);
  float* ru0 = (float*)alloc((size_t)NB * 128 * 4);
  float* ru1 = (float*)alloc((size_t)NB * 128 * 4);
  float* P0  = (float*)alloc((size_t)NB * HH * 4);
  float* P1  = (float*)alloc((size_t)NB * HH * 4);
  float* st1 = (float*)alloc((size_t)NB * HH * 4);
  float* decin = (float*)alloc((size_t)NB * 4);
  float* xin = (float*)alloc((size_t)TT * NB * 2 * 4);
  u16* STh = h1h;
  u16* STl = h1l;
  u16* YcC0h = YcR0h; u16* YcC0l = YcR0l;
  u16* YcC1h = YcR1h; u16* YcC1l = YcR1l;

  const int wKTa[4]  = {384, 640, 384, 640};
  const int wIndim[4]= {2, 64, 1, 64};
  const int wDp[4]   = {72, 128, 72, 128};
  u16 *Wrh[4], *Wrl[4], *Wch[4], *Wcl[4];
  for (int i = 0; i < 4; i++) {
    Wrh[i] = (u16*)alloc((size_t)128 * wKTa[i] * 2);
    Wrl[i] = (u16*)alloc((size_t)128 * wKTa[i] * 2);
    Wch[i] = (u16*)alloc((size_t)64 * wKTa[i] * 2);
    Wcl[i] = (u16*)alloc((size_t)64 * wKTa[i] * 2);
  }

  auto blocks = [](int n) { return (n + 255) / 256; };
  k_zero<<<blocks(NB * HH), 256, 0, stream>>>(P1, NB * HH);
  k_zero<<<blocks(NB * HH), 256, 0, stream>>>(st1, NB * HH);
  k_zero<<<blocks(NB), 256, 0, stream>>>(decin, NB);
  k_transpose_in<<<blocks(BB * TT * NN * 2), 256, 0, stream>>>(inputs, xin);
  k_splitS<<<blocks(2 * NN * NN), 256, 0, stream>>>(supports, Sh, Sl);
  k_transpS<<<blocks(2 * NN * NN), 256, 0, stream>>>(Sh, Sl, STh, STl);
  k_sq<<<128, 256, 0, stream>>>(Sh, Sl, STh, STl,
                                Sh + (size_t)2 * NN * NN,
                                Sl + (size_t)2 * NN * NN);
  k_init1<<<blocks(16 * 64 * NN), 256, 0, stream>>>(YcR1h, YcR1l, h1h, h1l);
  for (int i = 0; i < 4; i++) {
    k_padWt<<<blocks(128 * wKTa[i]), 256, 0, stream>>>(
        Wsrc[2 * i], Wrh[i], Wrl[i], wIndim[i], wDp[i], wKTa[i], 128);
    k_padWtCand<<<blocks(64 * wKTa[i]), 256, 0, stream>>>(
        Wsrc[2 * i + 1], Wch[i], Wcl[i], wIndim[i], wDp[i], wKTa[i], 64);
  }

  LayerH L[4];
  for (int i = 0; i < 4; i++) {
    bool lo = (wDp[i] == 72);
    L[i].YcRh = lo ? YcR0h : YcR1h; L[i].YcRl = lo ? YcR0l : YcR1l;
    L[i].YcCh = lo ? YcC0h : YcC1h; L[i].YcCl = lo ? YcC0l : YcC1l;
    L[i].hh = lo ? h0h : h1h; L[i].hl = lo ? h0l : h1l;
    L[i].ru = lo ? ru0 : ru1;
    L[i].Wrh = Wrh[i]; L[i].Wrl = Wrl[i]; L[i].Wch = Wch[i]; L[i].Wcl = Wcl[i];
    L[i].br = bias[2 * i]; L[i].bc = bias[2 * i + 1];
    L[i].indim = wIndim[i];
    L[i].CW = wDp[i]; L[i].KTa = wKTa[i]; L[i].STR = wKTa[i] + 64;
    L[i].nfull = lo ? 576 : 512;
  }

  auto prepSeg = [&](LayerH& Y, const float* inp, const float* st) {
    return PrepSeg{inp, st, Y.YcRh, Y.YcRl, Y.hh, Y.hl, Y.indim, Y.CW, Y.STR, BB * Y.CW};
  };
  auto dRuSeg = [&](LayerH& Y) {
    return DiffSeg{Y.YcRh, Y.YcRl, Y.hh, Y.hl, Y.nfull};
  };
  auto dCdSeg = [&](LayerH& Y) {
    return DiffSeg{Y.YcCh, Y.YcCl, Y.hh, Y.hl, 512};
  };
  auto ruSeg = [&](LayerH& Y, const float* stold) {
    return G3RuSeg{Y.hh, Y.hl, Y.Wrh, Y.Wrl, Y.br, stold, Y.ru,
                   Y.YcCh, Y.YcCl, Y.hh, Y.hl, Y.KTa, Y.STR, NB / 64};
  };
  auto cdSeg = [&](LayerH& Y, const float* stold, float* stout,
                   const float* ow, const float* ob, int t) {
    G3CdSeg g{};
    g.Ah = Y.hh; g.Al = Y.hl; g.Bh = Y.Wch; g.Bl = Y.Wcl;
    g.bias = Y.bc; g.ru = Y.ru; g.stold = stold; g.stout = stout;
    g.ow = ow; g.ob = ob; g.outg = out; g.decin = decin;
    g.t = t; g.KTa = Y.KTa; g.STR = Y.STR; g.nblk = NB / 64;
    return g;
  };
  auto tgtA = [&](G3CdSeg& g, LayerH& Y, int base) {
    g.yAh = Y.YcRh; g.yAl = Y.YcRl; g.hAh = Y.hh; g.hAl = Y.hl;
    g.cwA = Y.CW; g.baseA = base; g.strA = Y.STR;
  };
  auto tgtB = [&](G3CdSeg& g, LayerH& Y, int base) {
    g.yBh = Y.YcRh; g.yBl = Y.YcRl; g.hBh = Y.hh; g.hBl = Y.hl;
    g.cwB = Y.CW; g.baseB = base; g.strB = Y.STR;
  };
  auto tgtX = [&](G3CdSeg& g, const float* xp) {
    g.xp = xp;
    g.yXh = L[0].YcRh; g.yXl = L[0].YcRl; g.hXh = L[0].hh; g.hXl = L[0].hl;
  };

  float* P[2] = {P0, P1};

  // ---- encoder t=0 ----
  {
    PrepSeg p = prepSeg(L[0], xin, P1);
    k_prepM<<<p.nblk, 256, 0, stream>>>(p, p);
    DiffSeg dr = dRuSeg(L[0]);
    k_diffM<0, -1><<<dr.nblk, 256, 0, stream>>>(dr, dr, Sh);
    G3RuSeg gr = ruSeg(L[0], P1);
    k_g3ru<<<gr.nblk, 512, 0, stream>>>(gr, gr);
    DiffSeg dc = dCdSeg(L[0]);
    k_diffM<2, -1><<<dc.nblk, 256, 0, stream>>>(dc, dc, Sh);
    G3CdSeg gc = cdSeg(L[0], P1, P0, nullptr, nullptr, 0);
    tgtA(gc, L[0], 0);
    tgtB(gc, L[1], 64);
    tgtX(gc, xin + (size_t)1 * NB * 2);
    k_g3cd<<<gc.nblk, 256, 0, stream>>>(gc, gc);
  }
  // ---- encoder steady ----
  for (int t = 1; t < TT; t++) {
    const float* Pold = P[(t - 1) & 1];
    float* Pnew = P[t & 1];
    DiffSeg dr0 = dRuSeg(L[0]), dr1 = dRuSeg(L[1]);
    k_diffM<0, 1><<<dr0.nblk + dr1.nblk, 256, 0, stream>>>(dr0, dr1, Sh);
    G3RuSeg gr0 = ruSeg(L[0], Pold), gr1 = ruSeg(L[1], st1);
    k_g3ru<<<gr0.nblk + gr1.nblk, 512, 0, stream>>>(gr0, gr1);
    DiffSeg dc0 = dCdSeg(L[0]), dc1 = dCdSeg(L[1]);
    k_diffM<2, 3><<<dc0.nblk + dc1.nblk, 256, 0, stream>>>(dc0, dc1, Sh);
    G3CdSeg gc0 = cdSeg(L[0], Pold, Pnew, nullptr, nullptr, 0);
    tgtA(gc0, L[0], 0);
    tgtB(gc0, L[1], 64);
    G3CdSeg gc1 = cdSeg(L[1], st1, st1, nullptr, nullptr, 0);
    tgtA(gc1, L[1], 0);
    if (t < TT - 1) tgtX(gc1, xin + (size_t)(t + 1) * NB * 2);
    k_g3cd<<<gc0.nblk + gc1.nblk, 256, 0, stream>>>(gc0, gc1);
  }
  // ---- encoder final l1 ----
  {
    DiffSeg dr = dRuSeg(L[1]);
    k_diffM<1, -1><<<dr.nblk, 256, 0, stream>>>(dr, dr, Sh);
    G3RuSeg gr = ruSeg(L[1], st1);
    k_g3ru<<<gr.nblk, 512, 0, stream>>>(gr, gr);
    DiffSeg dc = dCdSeg(L[1]);
    k_diffM<3, -1><<<dc.nblk, 256, 0, stream>>>(dc, dc, Sh);
    G3CdSeg gc = cdSeg(L[1], st1, st1, nullptr, nullptr, 0);
    k_g3cd<<<gc.nblk, 256, 0, stream>>>(gc, gc);
  }

  // ---- decoder ----
  {
    PrepSeg pd0 = prepSeg(L[2], decin, P1);
    PrepSeg pd1 = prepSeg(L[3], P1, st1);
    k_prepM<<<pd0.nblk + pd1.nblk, 256, 0, stream>>>(pd0, pd1);
  }
  for (int t = 0; t < TT; t++) {
    DiffSeg dr0 = dRuSeg(L[2]);
    k_diffM<0, -1><<<dr0.nblk, 256, 0, stream>>>(dr0, dr0, Sh);
    G3RuSeg gr0 = ruSeg(L[2], P1);
    k_g3ru<<<gr0.nblk, 512, 0, stream>>>(gr0, gr0);
    DiffSeg dc0 = dCdSeg(L[2]);
    k_diffM<2, -1><<<dc0.nblk, 256, 0, stream>>>(dc0, dc0, Sh);
    G3CdSeg g0 = cdSeg(L[2], P1, P1, nullptr, nullptr, 0);
    tgtA(g0, L[2], 0);
    tgtB(g0, L[3], 64);
    k_g3cd<<<g0.nblk, 256, 0, stream>>>(g0, g0);
    DiffSeg dr1 = dRuSeg(L[3]);
    k_diffM<1, -1><<<dr1.nblk, 256, 0, stream>>>(dr1, dr1, Sh);
    G3RuSeg gr1 = ruSeg(L[3], st1);
    k_g3ru<<<gr1.nblk, 512, 0, stream>>>(gr1, gr1);
    DiffSeg dc1 = dCdSeg(L[3]);
    k_diffM<3, -1><<<dc1.nblk, 256, 0, stream>>>(dc1, dc1, Sh);
    G3CdSeg g1 = cdSeg(L[3], st1, st1, outW, outB, t);
    tgtA(g1, L[3], 0);
    g1.yPh = L[2].YcRh; g1.yPl = L[2].YcRl; g1.hPh = L[2].hh; g1.hPl = L[2].hl;
    g1.cwP = 72; g1.baseP = 64; g1.strP = 448;
    k_g3cd<<<g1.nblk, 256, 0, stream>>>(g1, g1);
  }
}